// Round 14
// baseline (5850.858 us; speedup 1.0000x reference)
//
#include <hip/hip_runtime.h>
#include <hip/hip_fp16.h>
#include <cstdint>
#include <cstddef>

// ---------------------------------------------------------------------------
// CNN (conv1+pool, conv2+pool) -> seq [256][256][32]
// NTM scan: 256 blocks x 1024 threads, 1 batch/block, 1 block/CU.
// R13 structure (2 __syncthreads + 2 LDS sub-barriers), plus:
//  - streamed GEMM loads manually software-pipelined (groups of 4 pairs,
//    8 uint4 prefetched while previous group's 32 dot2s execute)
//  - WrT laid out [3][1024] uint4 (coalesced LSTM reads-term loads)
//  - subsync: poll once then s_sleep(2) loop
// REGION i: waves 0..7 z-GEMM(i) | waves 8..13 chain(i-1) P3/P4/P5 |
//           wave 14 x-prefetch.  Then LSTM(i).
// ---------------------------------------------------------------------------

#define MW    20
#define NLOC  128
#define ZC    1024
#define PC    92
#define CLIPV 20.0f

__device__ __forceinline__ float sigmoidf_(float x) { return 1.0f / (1.0f + expf(-x)); }
__device__ __forceinline__ float softplusf_(float x) { return log1pf(expf(x)); }

__device__ __forceinline__ float dot2f(uint32_t w, uint32_t a, float c) {
    asm("v_dot2_f32_f16 %0, %1, %2, %0" : "+v"(c) : "v"(w), "v"(a));
    return c;
}

// pair row map (144 pairs): k<32 -> wx row k (x); k in [32,288) -> wh row k-32
__device__ __forceinline__ float wvalA(const float* wx, const float* wh, int k, int col) {
    return (k < 32) ? wx[k * ZC + col] : wh[(k - 32) * ZC + col];
}
__device__ __forceinline__ uint32_t packA(const float* wx, const float* wh, int pr, int col) {
    __half2 h = __floats2half2_rn(wvalA(wx, wh, 2 * pr, col), wvalA(wx, wh, 2 * pr + 1, col));
    return *reinterpret_cast<uint32_t*>(&h);
}

// WG8: u32 idx = ((pr*2 + j)*128 + c)*4 + m -> col = 8c + 4j + m, pr 0..143.
// WrT: u32 idx = ((j*1024)+col)*4 + qq, pair q=j*4+qq (q<10: wx rows 32..51).
// hw2: [128 up][92 col] u32.
__global__ __launch_bounds__(256) void prep_pack(const float* __restrict__ wx,
                                                 const float* __restrict__ wh,
                                                 const float* __restrict__ hw,
                                                 uint32_t* __restrict__ WG8,
                                                 uint32_t* __restrict__ WrT,
                                                 uint32_t* __restrict__ hw2) {
    int idx = blockIdx.x * 256 + threadIdx.x;
    if (idx < 147456) {
        int m = idx & 3, c = (idx >> 2) & 127, j = (idx >> 9) & 1, pr = idx >> 10;
        WG8[idx] = packA(wx, wh, pr, 8 * c + 4 * j + m);
    } else if (idx < 159744) {
        int q2 = idx - 147456;
        int qq = q2 & 3, col = (q2 >> 2) & 1023, j = q2 >> 12;
        int q = j * 4 + qq;
        if (q < 10) {
            __half2 h = __floats2half2_rn(wx[(32 + 2 * q) * ZC + col], wx[(33 + 2 * q) * ZC + col]);
            WrT[q2] = *reinterpret_cast<uint32_t*>(&h);
        } else WrT[q2] = 0u;
    } else if (idx < 171520) {
        int q3 = idx - 159744;
        int up = q3 / 92, col = q3 - up * 92;
        __half2 h = __floats2half2_rn(hw[(2 * up) * PC + col], hw[(2 * up + 1) * PC + col]);
        hw2[q3] = *reinterpret_cast<uint32_t*>(&h);
    }
}

// conv1 3x3 (1->16) SAME + relu + maxpool2
__global__ __launch_bounds__(256) void conv1_pool(const float* __restrict__ in,
                                                  const float* __restrict__ w,
                                                  const float* __restrict__ bias,
                                                  float* __restrict__ out) {
    int idx = blockIdx.x * 256 + threadIdx.x;
    if (idx >= 256 * 32 * 32 * 16) return;
    int c = idx & 15, x = (idx >> 4) & 31, y = (idx >> 9) & 31, b = idx >> 14;
    const float* inb = in + (size_t)b * 4096;
    float bv = bias[c];
    float mx = 0.0f;
    #pragma unroll
    for (int dy = 0; dy < 2; ++dy)
    #pragma unroll
    for (int dx = 0; dx < 2; ++dx) {
        int oy = 2 * y + dy, ox = 2 * x + dx;
        float s = bv;
        #pragma unroll
        for (int ky = 0; ky < 3; ++ky) {
            int iy = oy + ky - 1;
            if (iy < 0 || iy > 63) continue;
            #pragma unroll
            for (int kx = 0; kx < 3; ++kx) {
                int ix = ox + kx - 1;
                if (ix < 0 || ix > 63) continue;
                s = fmaf(inb[iy * 64 + ix], w[(ky * 3 + kx) * 16 + c], s);
            }
        }
        mx = fmaxf(mx, fmaxf(s, 0.0f));
    }
    out[idx] = mx;
}

// conv2 3x3 (16->32) SAME + relu + maxpool2
__global__ __launch_bounds__(256) void conv2_pool(const float* __restrict__ p1,
                                                  const float* __restrict__ w,
                                                  const float* __restrict__ bias,
                                                  float* __restrict__ seq) {
    int idx = blockIdx.x * 256 + threadIdx.x;
    if (idx >= 256 * 16 * 16 * 32) return;
    int c = idx & 31, x = (idx >> 5) & 15, y = (idx >> 9) & 15, b = idx >> 13;
    const float* pb = p1 + (size_t)b * (32 * 32 * 16);
    float bv = bias[c];
    float acc[4] = {bv, bv, bv, bv};
    #pragma unroll
    for (int ky = 0; ky < 3; ++ky)
    #pragma unroll
    for (int kx = 0; kx < 3; ++kx) {
        float w16[16];
        #pragma unroll
        for (int i = 0; i < 16; ++i) w16[i] = w[((ky * 3 + kx) * 16 + i) * 32 + c];
        #pragma unroll
        for (int dy = 0; dy < 2; ++dy)
        #pragma unroll
        for (int dx = 0; dx < 2; ++dx) {
            int iy = 2 * y + dy + ky - 1, ix = 2 * x + dx + kx - 1;
            if (iy < 0 || iy > 31 || ix < 0 || ix > 31) continue;
            const float4* pin4 = (const float4*)(pb + (iy * 32 + ix) * 16);
            float4 v0 = pin4[0], v1 = pin4[1], v2 = pin4[2], v3 = pin4[3];
            int a = dy * 2 + dx;
            acc[a] = fmaf(v0.x, w16[0], acc[a]);  acc[a] = fmaf(v0.y, w16[1], acc[a]);
            acc[a] = fmaf(v0.z, w16[2], acc[a]);  acc[a] = fmaf(v0.w, w16[3], acc[a]);
            acc[a] = fmaf(v1.x, w16[4], acc[a]);  acc[a] = fmaf(v1.y, w16[5], acc[a]);
            acc[a] = fmaf(v1.z, w16[6], acc[a]);  acc[a] = fmaf(v1.w, w16[7], acc[a]);
            acc[a] = fmaf(v2.x, w16[8], acc[a]);  acc[a] = fmaf(v2.y, w16[9], acc[a]);
            acc[a] = fmaf(v2.z, w16[10], acc[a]); acc[a] = fmaf(v2.w, w16[11], acc[a]);
            acc[a] = fmaf(v3.x, w16[12], acc[a]); acc[a] = fmaf(v3.y, w16[13], acc[a]);
            acc[a] = fmaf(v3.z, w16[14], acc[a]); acc[a] = fmaf(v3.w, w16[15], acc[a]);
        }
    }
    float mx = 0.0f;
    #pragma unroll
    for (int a = 0; a < 4; ++a) mx = fmaxf(mx, acc[a]);
    seq[idx] = mx;
}

// ---------------------------------------------------------------------------
// Persistent NTM scan, wave-specialized + software-pipelined GEMM stream.
// ---------------------------------------------------------------------------
#define PSCLIP1(col_) fminf(fmaxf(pp[0][col_] + pp[1][col_] + pp[2][col_] + pp[3][col_] + hb[col_], -CLIPV), CLIPV)

#define D8(w0_, w1_, av_) \
    a0 = dot2f(w0_.x, av_, a0); a1 = dot2f(w0_.y, av_, a1); \
    a2 = dot2f(w0_.z, av_, a2); a3 = dot2f(w0_.w, av_, a3); \
    a4 = dot2f(w1_.x, av_, a4); a5 = dot2f(w1_.y, av_, a5); \
    a6 = dot2f(w1_.z, av_, a6); a7 = dot2f(w1_.w, av_, a7);

__global__ __launch_bounds__(1024, 4) void ntm_scan14(
    const float* __restrict__ seq,
    const uint32_t* __restrict__ WG8,
    const uint32_t* __restrict__ WrT,
    const uint32_t* __restrict__ hw2G,
    const float* __restrict__ lb,
    const float* __restrict__ hb,
    const float* __restrict__ ow,
    const float* __restrict__ ob,
    const float* __restrict__ dw,
    const float* __restrict__ db,
    float* __restrict__ out)          // [256][2]
{
    __shared__ uint4 Wl4[32 * 2 * 128];               // 131072 B (8 pairs per K-quarter)
    __shared__ float zpart[4][ZC];                    // 16384 B
    __shared__ __align__(16) uint32_t aci[160];       // 640 B (x 0..15, h 16..143)
    __shared__ uint32_t xbuf[16];                     // 64 B
    __shared__ float Msh[MW][132];                    // 10560 B
    __shared__ float wprev[2][NLOC];                  // 1024 B
    __shared__ float pp[4][PC];                       // 1472 B
    __shared__ float evs[MW], avs[MW], rds[MW];       // 240 B
    __shared__ uint32_t rp[10];                       // 40 B
    __shared__ float o8[8];                           // 32 B
    __shared__ int sflag;                             // 4 B
    // total ~161.5 KB -> 1 block/CU

    const int t = threadIdx.x;
    const int bb = blockIdx.x;
    const uint4* WGV = (const uint4*)WG8;

    // ---- stage resident pairs: per K-quarter kq (36 pairs), pairs 0..7 ----
    for (int i = t; i < 8192; i += 1024) {
        int lp = i >> 8, j = (i >> 7) & 1, c = i & 127;
        int gp = (lp >> 3) * 36 + (lp & 7);
        Wl4[i] = WGV[(gp * 2 + j) * 128 + c];
    }

    // ---- init state ----
    if (t < 160) {
        uint32_t v = 0u;
        if (t < 16) {
            __half2 hh2 = __floats2half2_rn(seq[(size_t)bb * 8192 + 2 * t],
                                            seq[(size_t)bb * 8192 + 2 * t + 1]);
            v = *reinterpret_cast<uint32_t*>(&hh2);
        }
        aci[t] = v;
    }
    for (int i = t; i < MW * 132; i += 1024)
        Msh[i / 132][i - (i / 132) * 132] = 1e-6f;
    if (t < 256) wprev[t >> 7][t & 127] = 1.0f / 128.0f;
    if (t < 10) {
        __half2 hh2 = __floats2half2_rn(1e-6f, 1e-6f);
        rp[t] = *reinterpret_cast<uint32_t*>(&hh2);
    }
    if (t == 0) sflag = 0;
    float c_reg = 0.0f;   // LSTM cell: thread t<256 owns u=t
    __syncthreads();

    int svc = 0;
    auto subsync = [&]() {
        svc += 6;
        __threadfence_block();
        if ((t & 63) == 0)
            __hip_atomic_fetch_add(&sflag, 1, __ATOMIC_RELAXED, __HIP_MEMORY_SCOPE_WORKGROUP);
        while (__hip_atomic_load(&sflag, __ATOMIC_RELAXED, __HIP_MEMORY_SCOPE_WORKGROUP) < svc)
            __builtin_amdgcn_s_sleep(2);
        __threadfence_block();
    };

    // ---- chain phase bodies (waves 8..13, pt = t-512) ----
    auto doP3 = [&](int pt) {
        if (pt < 368) {
            int kq2 = pt / 92, col = pt - kq2 * 92;
            const uint32_t* hwp = hw2G + kq2 * 32 * 92 + col;
            const uint32_t* hbp = aci + 16 + kq2 * 32;
            float s = 0.0f;
            #pragma unroll 8
            for (int uu = 0; uu < 32; ++uu)
                s = dot2f(hwp[uu * 92], hbp[uu], s);
            pp[kq2][col] = s;
        }
    };
    auto doP4 = [&](int pt) {
        if (pt < 128) {
            const int l = pt & 63, hh = pt >> 6;
            const int hc = hh * 26;
            float beta  = softplusf_(PSCLIP1(hc + 20));
            float gte   = sigmoidf_(PSCLIP1(hc + 21));
            float s0r = PSCLIP1(hc + 22), s1r = PSCLIP1(hc + 23), s2r = PSCLIP1(hc + 24);
            float mS = fmaxf(s0r, fmaxf(s1r, s2r));
            float q0 = expf(s0r - mS), q1 = expf(s1r - mS), q2 = expf(s2r - mS);
            float qin = 1.0f / (q0 + q1 + q2);
            float sh0 = q0 * qin, sh1 = q1 * qin, sh2 = q2 * qin;
            float gamma = softplusf_(PSCLIP1(hc + 25)) + 1.0f;

            float kvv = (l < 20) ? tanhf(PSCLIP1(hc + l)) : 0.0f;
            float kn2 = kvv * kvv;
            #pragma unroll
            for (int o = 1; o < 64; o <<= 1) kn2 += __shfl_xor(kn2, o, 64);
            float kden = sqrtf(kn2) + 1e-8f;

            float d0 = 0, d1 = 0, m20 = 0, m21 = 0;
            #pragma unroll
            for (int wi = 0; wi < 20; ++wi) {
                float kk = __shfl(kvv, wi, 64);
                float2 mv = *reinterpret_cast<const float2*>(&Msh[wi][2 * l]);
                d0  = fmaf(kk, mv.x, d0);      d1  = fmaf(kk, mv.y, d1);
                m20 = fmaf(mv.x, mv.x, m20);   m21 = fmaf(mv.y, mv.y, m21);
            }
            float x0 = beta * (d0 / ((sqrtf(m20) + 1e-8f) * kden));
            float x1 = beta * (d1 / ((sqrtf(m21) + 1e-8f) * kden));
            float mx = fmaxf(x0, x1);
            #pragma unroll
            for (int o = 1; o < 64; o <<= 1) mx = fmaxf(mx, __shfl_xor(mx, o, 64));
            float e0 = expf(x0 - mx), e1 = expf(x1 - mx);
            float se = e0 + e1;
            #pragma unroll
            for (int o = 1; o < 64; o <<= 1) se += __shfl_xor(se, o, 64);
            float inv = 1.0f / se;
            float2 wpv = *reinterpret_cast<const float2*>(&wprev[hh][2 * l]);
            float wg0 = gte * (e0 * inv) + (1.0f - gte) * wpv.x;
            float wg1 = gte * (e1 * inv) + (1.0f - gte) * wpv.y;
            float wgm = __shfl(wg1, (l + 63) & 63, 64);
            float wgp = __shfl(wg0, (l + 1) & 63, 64);
            float wt0 = sh0 * wg1 + sh1 * wg0 + sh2 * wgm;
            float wt1 = sh0 * wgp + sh1 * wg1 + sh2 * wg0;
            float wpw0 = expf(gamma * logf(wt0 + 1e-8f));
            float wpw1 = expf(gamma * logf(wt1 + 1e-8f));
            float ssum = wpw0 + wpw1;
            #pragma unroll
            for (int o = 1; o < 64; o <<= 1) ssum += __shfl_xor(ssum, o, 64);
            float rin = 1.0f / ssum;
            *reinterpret_cast<float2*>(&wprev[hh][2 * l]) = make_float2(wpw0 * rin, wpw1 * rin);
        } else if (pt < 168) {
            int r2 = pt - 128;
            if (r2 < 20) evs[r2]      = sigmoidf_(PSCLIP1(52 + r2));
            else         avs[r2 - 20] = tanhf(PSCLIP1(72 + (r2 - 20)));
        }
    };
    auto doP5 = [&](int pt) {
        if (pt < 320) {
            int wi = pt >> 4, l16 = pt & 15;
            int n0 = l16 * 8;
            float ev = evs[wi], av = avs[wi];
            float s = 0.0f;
            #pragma unroll
            for (int n = n0; n < n0 + 8; ++n) {
                float mv = Msh[wi][n];
                s = fmaf(wprev[0][n], mv, s);
                float wwn = wprev[1][n];
                Msh[wi][n] = mv * (1.0f - wwn * ev) + wwn * av;
            }
            s += __shfl_xor(s, 1, 64); s += __shfl_xor(s, 2, 64);
            s += __shfl_xor(s, 4, 64); s += __shfl_xor(s, 8, 64);
            float sodd = __shfl_xor(s, 16, 64);
            if (l16 == 0) {
                rds[wi] = s;
                if ((wi & 1) == 0) {
                    __half2 hp = __floats2half2_rn(s, sodd);
                    rp[wi >> 1] = *reinterpret_cast<uint32_t*>(&hp);
                }
            }
        }
    };

    for (int i = 0; i < 256; ++i) {
        // ========= REGION: z-GEMM(i) || chain(i-1) || x-prefetch =========
        if (t < 512) {
            const int kq = t >> 7, c = t & 127;
            const int prb = kq * 36;
            float a0 = 0, a1 = 0, a2 = 0, a3 = 0, a4 = 0, a5 = 0, a6 = 0, a7 = 0;
            const uint4* cap = (const uint4*)(aci + prb);

            // prefetch streamed group g=2 (pairs 8..11): 8 uint4
            uint4 p0a, p0b, p1a, p1b, p2a, p2b, p3a, p3b;
            {
                const uint4* wgp = WGV + (size_t)(prb + 8) * 256 + c;
                p0a = wgp[0];   p0b = wgp[128];
                p1a = wgp[256]; p1b = wgp[384];
                p2a = wgp[512]; p2b = wgp[640];
                p3a = wgp[768]; p3b = wgp[896];
            }

            // resident pairs 0..7 from LDS while stream arrives
            {
                uint4 A0 = cap[0], A1 = cap[1];
                uint32_t act[8] = {A0.x, A0.y, A0.z, A0.w, A1.x, A1.y, A1.z, A1.w};
                #pragma unroll
                for (int p = 0; p < 8; ++p) {
                    uint4 w0 = Wl4[((kq * 8 + p) * 2 + 0) * 128 + c];
                    uint4 w1 = Wl4[((kq * 8 + p) * 2 + 1) * 128 + c];
                    D8(w0, w1, act[p])
                }
            }

            // streamed pairs 8..35 in 7 groups of 4, software-pipelined
            #pragma unroll
            for (int g = 2; g < 9; ++g) {
                uint4 w0a = p0a, w0b = p0b, w1a = p1a, w1b = p1b;
                uint4 w2a = p2a, w2b = p2b, w3a = p3a, w3b = p3b;
                if (g < 8) {
                    const uint4* wgp = WGV + (size_t)(prb + (g + 1) * 4) * 256 + c;
                    p0a = wgp[0];   p0b = wgp[128];
                    p1a = wgp[256]; p1b = wgp[384];
                    p2a = wgp[512]; p2b = wgp[640];
                    p3a = wgp[768]; p3b = wgp[896];
                }
                uint4 A = cap[g];
                D8(w0a, w0b, A.x)
                D8(w1a, w1b, A.y)
                D8(w2a, w2b, A.z)
                D8(w3a, w3b, A.w)
            }
            *reinterpret_cast<float4*>(&zpart[kq][8 * c])     = make_float4(a0, a1, a2, a3);
            *reinterpret_cast<float4*>(&zpart[kq][8 * c + 4]) = make_float4(a4, a5, a6, a7);
        } else if (t < 896) {
            if (i > 0) {
                const int pt = t - 512;
                doP3(pt);
                subsync();
                doP4(pt);
                subsync();
                doP5(pt);
            }
        } else if (t < 912 && i < 255) {
            int j = t - 896;
            const float* xp = seq + (size_t)bb * 8192 + (size_t)(i + 1) * 32 + 2 * j;
            __half2 hh2 = __floats2half2_rn(xp[0], xp[1]);
            xbuf[j] = *reinterpret_cast<uint32_t*>(&hh2);
        }
        __syncthreads();   // B1

        // ========= LSTM i (+ xbuf -> aci copy) =========
        if (t < 256) {
            uint32_t rp0 = rp[0], rp1 = rp[1], rp2 = rp[2], rp3 = rp[3];
            uint32_t rp4 = rp[4], rp5 = rp[5], rp6 = rp[6], rp7 = rp[7];
            uint32_t rp8 = rp[8], rp9 = rp[9];
            const uint4* wrt4 = (const uint4*)WrT;   // [3][1024] uint4
            float zg4[4];
            #pragma unroll
            for (int g4 = 0; g4 < 4; ++g4) {
                const int colu = (g4 << 8) + t;
                uint4 A = wrt4[colu];
                uint4 B = wrt4[1024 + colu];
                uint4 C = wrt4[2048 + colu];
                float s = 0.0f;
                s = dot2f(A.x, rp0, s); s = dot2f(A.y, rp1, s);
                s = dot2f(A.z, rp2, s); s = dot2f(A.w, rp3, s);
                s = dot2f(B.x, rp4, s); s = dot2f(B.y, rp5, s);
                s = dot2f(B.z, rp6, s); s = dot2f(B.w, rp7, s);
                s = dot2f(C.x, rp8, s); s = dot2f(C.y, rp9, s);
                zg4[g4] = s;
            }
            float zi = lb[t]       + zg4[0] + zpart[0][t]       + zpart[1][t]       + zpart[2][t]       + zpart[3][t];
            float zf = lb[256 + t] + zg4[1] + zpart[0][256 + t] + zpart[1][256 + t] + zpart[2][256 + t] + zpart[3][256 + t];
            float zg = lb[512 + t] + zg4[2] + zpart[0][512 + t] + zpart[1][512 + t] + zpart[2][512 + t] + zpart[3][512 + t];
            float zo = lb[768 + t] + zg4[3] + zpart[0][768 + t] + zpart[1][768 + t] + zpart[2][768 + t] + zpart[3][768 + t];
            float cg = sigmoidf_(zf) * c_reg + sigmoidf_(zi) * tanhf(zg);
            c_reg = cg;
            reinterpret_cast<_Float16*>(aci)[32 + t] = (_Float16)(sigmoidf_(zo) * tanhf(cg));
        } else if (t >= 256 && t < 272 && i < 255) {
            aci[t - 256] = xbuf[t - 256];
        }
        __syncthreads();   // B2
    }

    // ---- epilogue: chain for step 255 ----
    if (t >= 512 && t < 896) {
        const int pt = t - 512;
        doP3(pt);
        subsync();
        doP4(pt);
        subsync();
        doP5(pt);
    }
    __syncthreads();

    // ---- final NTM output head + dense + softmax ----
    if (t < 8) {
        float s = ob[t];
        const _Float16* hrow = reinterpret_cast<const _Float16*>(aci);
        for (int u = 0; u < 256; ++u) s = fmaf((float)hrow[32 + u], ow[u * 8 + t], s);
        #pragma unroll
        for (int wi = 0; wi < 20; ++wi) s = fmaf(rds[wi], ow[(256 + wi) * 8 + t], s);
        o8[t] = fminf(fmaxf(s, -CLIPV), CLIPV);
    }
    __syncthreads();
    if (t == 0) {
        float l0 = db[0], l1 = db[1];
        #pragma unroll
        for (int k = 0; k < 8; ++k) {
            float v = o8[k];
            l0 = fmaf(v, dw[k * 2 + 0], l0);
            l1 = fmaf(v, dw[k * 2 + 1], l1);
        }
        float m = fmaxf(l0, l1);
        float q0 = expf(l0 - m), q1 = expf(l1 - m);
        float inv = 1.0f / (q0 + q1);
        out[bb * 2 + 0] = q0 * inv;
        out[bb * 2 + 1] = q1 * inv;
    }
}

extern "C" void kernel_launch(void* const* d_in, const int* in_sizes, int n_in,
                              void* d_out, int out_size, void* d_ws, size_t ws_size,
                              hipStream_t stream) {
    const float* inputs = (const float*)d_in[0];
    const float* c1w = (const float*)d_in[1];
    const float* c1b = (const float*)d_in[2];
    const float* c2w = (const float*)d_in[3];
    const float* c2b = (const float*)d_in[4];
    const float* lwx = (const float*)d_in[5];
    const float* lwh = (const float*)d_in[6];
    const float* lb  = (const float*)d_in[7];
    const float* hw  = (const float*)d_in[8];
    const float* hb  = (const float*)d_in[9];
    const float* ow  = (const float*)d_in[10];
    const float* ob  = (const float*)d_in[11];
    const float* dw  = (const float*)d_in[12];
    const float* db  = (const float*)d_in[13];
    float* out = (float*)d_out;

    float* ws  = (float*)d_ws;
    float* p1  = ws;                             // 4,194,304 f
    float* seq = ws + 4194304;                   // 2,097,152 f
    uint32_t* WG8  = (uint32_t*)(ws + 6291456);  // 147,456 u32
    uint32_t* WrT  = WG8 + 147456;               //  12,288 u32
    uint32_t* hw2G = WrT + 12288;                //  11,776 u32

    hipLaunchKernelGGL(prep_pack,   dim3(670),   dim3(256),  0, stream, lwx, lwh, hw, WG8, WrT, hw2G);
    hipLaunchKernelGGL(conv1_pool,  dim3(16384), dim3(256),  0, stream, inputs, c1w, c1b, p1);
    hipLaunchKernelGGL(conv2_pool,  dim3(8192),  dim3(256),  0, stream, p1, c2w, c2b, seq);
    hipLaunchKernelGGL(ntm_scan14,  dim3(256),   dim3(1024), 0, stream,
                       seq, WG8, WrT, hw2G, lb, hb, ow, ob, dw, db, out);
}

// Round 15
// 3701.258 us; speedup vs baseline: 1.5808x; 1.5808x over previous
//
#include <hip/hip_runtime.h>
#include <hip/hip_fp16.h>
#include <cstdint>
#include <cstddef>

// ---------------------------------------------------------------------------
// CNN (conv1+pool, conv2+pool) -> seq [256][256][32]
// NTM scan: 256 blocks x 1024 threads, 1 batch/block, 1 block/CU.
// R13 skeleton (2 __syncthreads + 2 LDS sub-barriers), rebalanced:
//  REGION i:
//    waves 0..11 : z-GEMM step i, 6 K-slices x 24 pairs (4 LDS-resident 96KB,
//                  20 streamed 480KB) -- 12 waves issuing loads (was 8)
//    waves 12..15: NTM chain step i-1:
//                  P3 (2-way K x 92 cols, 184t) + x-prefetch (16t)
//                  -[subsync]- P4 (128t) + e/a (40t) -[subsync]- P5 (160t,
//                  8-lane groups)
//  LSTM i: z = sum(6 zparts) + WrT*rp + bias -> h_i (WrT coalesced [3][1024]).
// No bulk register state anywhere near a barrier (R3/R4/R8/R14: 64-VGPR cap).
// ---------------------------------------------------------------------------

#define MW    20
#define NLOC  128
#define ZC    1024
#define PC    92
#define CLIPV 20.0f

__device__ __forceinline__ float sigmoidf_(float x) { return 1.0f / (1.0f + expf(-x)); }
__device__ __forceinline__ float softplusf_(float x) { return log1pf(expf(x)); }

__device__ __forceinline__ float dot2f(uint32_t w, uint32_t a, float c) {
    asm("v_dot2_f32_f16 %0, %1, %2, %0" : "+v"(c) : "v"(w), "v"(a));
    return c;
}

// pair row map (144 pairs): k<32 -> wx row k (x); k in [32,288) -> wh row k-32
__device__ __forceinline__ float wvalA(const float* wx, const float* wh, int k, int col) {
    return (k < 32) ? wx[k * ZC + col] : wh[(k - 32) * ZC + col];
}
__device__ __forceinline__ uint32_t packA(const float* wx, const float* wh, int pr, int col) {
    __half2 h = __floats2half2_rn(wvalA(wx, wh, 2 * pr, col), wvalA(wx, wh, 2 * pr + 1, col));
    return *reinterpret_cast<uint32_t*>(&h);
}

// WG8: u32 idx = ((pr*2 + j)*128 + c)*4 + m -> col = 8c + 4j + m, pr 0..143.
// WrT: u32 idx = ((j*1024)+col)*4 + qq, pair q = j*4+qq (q<10: wx rows 32..51).
// hw2: [128 up][92 col] u32.
__global__ __launch_bounds__(256) void prep_pack(const float* __restrict__ wx,
                                                 const float* __restrict__ wh,
                                                 const float* __restrict__ hw,
                                                 uint32_t* __restrict__ WG8,
                                                 uint32_t* __restrict__ WrT,
                                                 uint32_t* __restrict__ hw2) {
    int idx = blockIdx.x * 256 + threadIdx.x;
    if (idx < 147456) {
        int m = idx & 3, c = (idx >> 2) & 127, j = (idx >> 9) & 1, pr = idx >> 10;
        WG8[idx] = packA(wx, wh, pr, 8 * c + 4 * j + m);
    } else if (idx < 159744) {
        int q2 = idx - 147456;
        int qq = q2 & 3, col = (q2 >> 2) & 1023, j = q2 >> 12;
        int q = j * 4 + qq;
        if (q < 10) {
            __half2 h = __floats2half2_rn(wx[(32 + 2 * q) * ZC + col], wx[(33 + 2 * q) * ZC + col]);
            WrT[q2] = *reinterpret_cast<uint32_t*>(&h);
        } else WrT[q2] = 0u;
    } else if (idx < 171520) {
        int q3 = idx - 159744;
        int up = q3 / 92, col = q3 - up * 92;
        __half2 h = __floats2half2_rn(hw[(2 * up) * PC + col], hw[(2 * up + 1) * PC + col]);
        hw2[q3] = *reinterpret_cast<uint32_t*>(&h);
    }
}

// conv1 3x3 (1->16) SAME + relu + maxpool2
__global__ __launch_bounds__(256) void conv1_pool(const float* __restrict__ in,
                                                  const float* __restrict__ w,
                                                  const float* __restrict__ bias,
                                                  float* __restrict__ out) {
    int idx = blockIdx.x * 256 + threadIdx.x;
    if (idx >= 256 * 32 * 32 * 16) return;
    int c = idx & 15, x = (idx >> 4) & 31, y = (idx >> 9) & 31, b = idx >> 14;
    const float* inb = in + (size_t)b * 4096;
    float bv = bias[c];
    float mx = 0.0f;
    #pragma unroll
    for (int dy = 0; dy < 2; ++dy)
    #pragma unroll
    for (int dx = 0; dx < 2; ++dx) {
        int oy = 2 * y + dy, ox = 2 * x + dx;
        float s = bv;
        #pragma unroll
        for (int ky = 0; ky < 3; ++ky) {
            int iy = oy + ky - 1;
            if (iy < 0 || iy > 63) continue;
            #pragma unroll
            for (int kx = 0; kx < 3; ++kx) {
                int ix = ox + kx - 1;
                if (ix < 0 || ix > 63) continue;
                s = fmaf(inb[iy * 64 + ix], w[(ky * 3 + kx) * 16 + c], s);
            }
        }
        mx = fmaxf(mx, fmaxf(s, 0.0f));
    }
    out[idx] = mx;
}

// conv2 3x3 (16->32) SAME + relu + maxpool2
__global__ __launch_bounds__(256) void conv2_pool(const float* __restrict__ p1,
                                                  const float* __restrict__ w,
                                                  const float* __restrict__ bias,
                                                  float* __restrict__ seq) {
    int idx = blockIdx.x * 256 + threadIdx.x;
    if (idx >= 256 * 16 * 16 * 32) return;
    int c = idx & 31, x = (idx >> 5) & 15, y = (idx >> 9) & 15, b = idx >> 13;
    const float* pb = p1 + (size_t)b * (32 * 32 * 16);
    float bv = bias[c];
    float acc[4] = {bv, bv, bv, bv};
    #pragma unroll
    for (int ky = 0; ky < 3; ++ky)
    #pragma unroll
    for (int kx = 0; kx < 3; ++kx) {
        float w16[16];
        #pragma unroll
        for (int i = 0; i < 16; ++i) w16[i] = w[((ky * 3 + kx) * 16 + i) * 32 + c];
        #pragma unroll
        for (int dy = 0; dy < 2; ++dy)
        #pragma unroll
        for (int dx = 0; dx < 2; ++dx) {
            int iy = 2 * y + dy + ky - 1, ix = 2 * x + dx + kx - 1;
            if (iy < 0 || iy > 31 || ix < 0 || ix > 31) continue;
            const float4* pin4 = (const float4*)(pb + (iy * 32 + ix) * 16);
            float4 v0 = pin4[0], v1 = pin4[1], v2 = pin4[2], v3 = pin4[3];
            int a = dy * 2 + dx;
            acc[a] = fmaf(v0.x, w16[0], acc[a]);  acc[a] = fmaf(v0.y, w16[1], acc[a]);
            acc[a] = fmaf(v0.z, w16[2], acc[a]);  acc[a] = fmaf(v0.w, w16[3], acc[a]);
            acc[a] = fmaf(v1.x, w16[4], acc[a]);  acc[a] = fmaf(v1.y, w16[5], acc[a]);
            acc[a] = fmaf(v1.z, w16[6], acc[a]);  acc[a] = fmaf(v1.w, w16[7], acc[a]);
            acc[a] = fmaf(v2.x, w16[8], acc[a]);  acc[a] = fmaf(v2.y, w16[9], acc[a]);
            acc[a] = fmaf(v2.z, w16[10], acc[a]); acc[a] = fmaf(v2.w, w16[11], acc[a]);
            acc[a] = fmaf(v3.x, w16[12], acc[a]); acc[a] = fmaf(v3.y, w16[13], acc[a]);
            acc[a] = fmaf(v3.z, w16[14], acc[a]); acc[a] = fmaf(v3.w, w16[15], acc[a]);
        }
    }
    float mx = 0.0f;
    #pragma unroll
    for (int a = 0; a < 4; ++a) mx = fmaxf(mx, acc[a]);
    seq[idx] = mx;
}

// ---------------------------------------------------------------------------
// Persistent NTM scan, wave-specialized; 12 GEMM waves / 4 chain waves.
// ---------------------------------------------------------------------------
#define PSCLIP1(col_) fminf(fmaxf(pp[0][col_] + pp[1][col_] + hb[col_], -CLIPV), CLIPV)

#define D8(w0_, w1_, av_) \
    a0 = dot2f(w0_.x, av_, a0); a1 = dot2f(w0_.y, av_, a1); \
    a2 = dot2f(w0_.z, av_, a2); a3 = dot2f(w0_.w, av_, a3); \
    a4 = dot2f(w1_.x, av_, a4); a5 = dot2f(w1_.y, av_, a5); \
    a6 = dot2f(w1_.z, av_, a6); a7 = dot2f(w1_.w, av_, a7);

__global__ __launch_bounds__(1024, 4) void ntm_scan15(
    const float* __restrict__ seq,
    const uint32_t* __restrict__ WG8,
    const uint32_t* __restrict__ WrT,
    const uint32_t* __restrict__ hw2G,
    const float* __restrict__ lb,
    const float* __restrict__ hb,
    const float* __restrict__ ow,
    const float* __restrict__ ob,
    const float* __restrict__ dw,
    const float* __restrict__ db,
    float* __restrict__ out)          // [256][2]
{
    __shared__ uint4 Wl4[24 * 2 * 128];               // 98304 B (4 pairs per K-sixth)
    __shared__ float zpart[6][ZC];                    // 24576 B
    __shared__ __align__(16) uint32_t aci[160];       // 640 B (x 0..15, h 16..143)
    __shared__ uint32_t xbuf[16];                     // 64 B
    __shared__ float Msh[MW][132];                    // 10560 B
    __shared__ float wprev[2][NLOC];                  // 1024 B
    __shared__ float pp[2][PC];                       // 736 B
    __shared__ float evs[MW], avs[MW], rds[MW];       // 240 B
    __shared__ uint32_t rp[10];                       // 40 B
    __shared__ float o8[8];                           // 32 B
    __shared__ int sflag;                             // 4 B
    // total ~136.2 KB -> 1 block/CU

    const int t = threadIdx.x;
    const int bb = blockIdx.x;
    const uint4* WGV = (const uint4*)WG8;

    // ---- stage resident pairs: per K-sixth s6 (24 pairs), pairs 0..3 ----
    for (int i = t; i < 6144; i += 1024) {
        int lp = i >> 8, j = (i >> 7) & 1, c = i & 127;
        int gp = (lp >> 2) * 24 + (lp & 3);
        Wl4[i] = WGV[(gp * 2 + j) * 128 + c];
    }

    // ---- init state ----
    if (t < 160) {
        uint32_t v = 0u;
        if (t < 16) {
            __half2 hh2 = __floats2half2_rn(seq[(size_t)bb * 8192 + 2 * t],
                                            seq[(size_t)bb * 8192 + 2 * t + 1]);
            v = *reinterpret_cast<uint32_t*>(&hh2);
        }
        aci[t] = v;
    }
    for (int i = t; i < MW * 132; i += 1024)
        Msh[i / 132][i - (i / 132) * 132] = 1e-6f;
    if (t < 256) wprev[t >> 7][t & 127] = 1.0f / 128.0f;
    if (t < 10) {
        __half2 hh2 = __floats2half2_rn(1e-6f, 1e-6f);
        rp[t] = *reinterpret_cast<uint32_t*>(&hh2);
    }
    if (t == 0) sflag = 0;
    float c_reg = 0.0f;   // LSTM cell: thread t<256 owns u=t
    __syncthreads();

    int svc = 0;
    auto subsync = [&]() {
        svc += 4;                       // 4 chain waves participate
        __threadfence_block();
        if ((t & 63) == 0)
            __hip_atomic_fetch_add(&sflag, 1, __ATOMIC_RELAXED, __HIP_MEMORY_SCOPE_WORKGROUP);
        while (__hip_atomic_load(&sflag, __ATOMIC_RELAXED, __HIP_MEMORY_SCOPE_WORKGROUP) < svc)
            __builtin_amdgcn_s_sleep(2);
        __threadfence_block();
    };

    // ---- chain phase bodies (waves 12..15, pt = t-768) ----
    auto doP3 = [&](int pt) {
        if (pt < 184) {
            int kq2 = pt / 92, col = pt - kq2 * 92;
            const uint32_t* hwp = hw2G + kq2 * 64 * 92 + col;
            const uint32_t* hbp = aci + 16 + kq2 * 64;
            float s = 0.0f;
            #pragma unroll 8
            for (int uu = 0; uu < 64; ++uu)
                s = dot2f(hwp[uu * 92], hbp[uu], s);
            pp[kq2][col] = s;
        }
    };
    auto doP4 = [&](int pt) {
        if (pt < 128) {
            const int l = pt & 63, hh = pt >> 6;
            const int hc = hh * 26;
            float beta  = softplusf_(PSCLIP1(hc + 20));
            float gte   = sigmoidf_(PSCLIP1(hc + 21));
            float s0r = PSCLIP1(hc + 22), s1r = PSCLIP1(hc + 23), s2r = PSCLIP1(hc + 24);
            float mS = fmaxf(s0r, fmaxf(s1r, s2r));
            float q0 = expf(s0r - mS), q1 = expf(s1r - mS), q2 = expf(s2r - mS);
            float qin = 1.0f / (q0 + q1 + q2);
            float sh0 = q0 * qin, sh1 = q1 * qin, sh2 = q2 * qin;
            float gamma = softplusf_(PSCLIP1(hc + 25)) + 1.0f;

            float kvv = (l < 20) ? tanhf(PSCLIP1(hc + l)) : 0.0f;
            float kn2 = kvv * kvv;
            #pragma unroll
            for (int o = 1; o < 64; o <<= 1) kn2 += __shfl_xor(kn2, o, 64);
            float kden = sqrtf(kn2) + 1e-8f;

            float d0 = 0, d1 = 0, m20 = 0, m21 = 0;
            #pragma unroll
            for (int wi = 0; wi < 20; ++wi) {
                float kk = __shfl(kvv, wi, 64);
                float2 mv = *reinterpret_cast<const float2*>(&Msh[wi][2 * l]);
                d0  = fmaf(kk, mv.x, d0);      d1  = fmaf(kk, mv.y, d1);
                m20 = fmaf(mv.x, mv.x, m20);   m21 = fmaf(mv.y, mv.y, m21);
            }
            float x0 = beta * (d0 / ((sqrtf(m20) + 1e-8f) * kden));
            float x1 = beta * (d1 / ((sqrtf(m21) + 1e-8f) * kden));
            float mx = fmaxf(x0, x1);
            #pragma unroll
            for (int o = 1; o < 64; o <<= 1) mx = fmaxf(mx, __shfl_xor(mx, o, 64));
            float e0 = expf(x0 - mx), e1 = expf(x1 - mx);
            float se = e0 + e1;
            #pragma unroll
            for (int o = 1; o < 64; o <<= 1) se += __shfl_xor(se, o, 64);
            float inv = 1.0f / se;
            float2 wpv = *reinterpret_cast<const float2*>(&wprev[hh][2 * l]);
            float wg0 = gte * (e0 * inv) + (1.0f - gte) * wpv.x;
            float wg1 = gte * (e1 * inv) + (1.0f - gte) * wpv.y;
            float wgm = __shfl(wg1, (l + 63) & 63, 64);
            float wgp = __shfl(wg0, (l + 1) & 63, 64);
            float wt0 = sh0 * wg1 + sh1 * wg0 + sh2 * wgm;
            float wt1 = sh0 * wgp + sh1 * wg1 + sh2 * wg0;
            float wpw0 = expf(gamma * logf(wt0 + 1e-8f));
            float wpw1 = expf(gamma * logf(wt1 + 1e-8f));
            float ssum = wpw0 + wpw1;
            #pragma unroll
            for (int o = 1; o < 64; o <<= 1) ssum += __shfl_xor(ssum, o, 64);
            float rin = 1.0f / ssum;
            *reinterpret_cast<float2*>(&wprev[hh][2 * l]) = make_float2(wpw0 * rin, wpw1 * rin);
        } else if (pt < 168 + 40) {
            // (pt in [128,168) handles e/a; window shifted to stay clear of P4 lanes)
            int r2 = pt - 128;
            if (r2 < 20) evs[r2]      = sigmoidf_(PSCLIP1(52 + r2));
            else if (r2 < 40) avs[r2 - 20] = tanhf(PSCLIP1(72 + (r2 - 20)));
        }
    };
    auto doP5 = [&](int pt) {
        if (pt < 160) {
            int wi = pt >> 3, l8 = pt & 7;
            int n0 = l8 * 16;
            float ev = evs[wi], av = avs[wi];
            float s = 0.0f;
            #pragma unroll
            for (int n = n0; n < n0 + 16; ++n) {
                float mv = Msh[wi][n];
                s = fmaf(wprev[0][n], mv, s);
                float wwn = wprev[1][n];
                Msh[wi][n] = mv * (1.0f - wwn * ev) + wwn * av;
            }
            s += __shfl_xor(s, 1, 64); s += __shfl_xor(s, 2, 64); s += __shfl_xor(s, 4, 64);
            float sodd = __shfl_xor(s, 8, 64);
            if (l8 == 0) {
                rds[wi] = s;
                if ((wi & 1) == 0) {
                    __half2 hp = __floats2half2_rn(s, sodd);
                    rp[wi >> 1] = *reinterpret_cast<uint32_t*>(&hp);
                }
            }
        }
    };

    for (int i = 0; i < 256; ++i) {
        // ========= REGION: z-GEMM(i) on 12 waves || chain(i-1) on 4 waves ====
        if (t < 768) {
            const int s6 = t >> 7, c = t & 127;
            const int prb = s6 * 24;
            float a0 = 0, a1 = 0, a2 = 0, a3 = 0, a4 = 0, a5 = 0, a6 = 0, a7 = 0;
            const uint4* cap = (const uint4*)(aci + prb);
            #pragma unroll
            for (int g = 0; g < 6; ++g) {
                uint4 A = cap[g];
                uint32_t aa[4] = {A.x, A.y, A.z, A.w};
                #pragma unroll
                for (int q = 0; q < 4; ++q) {
                    const int p = g * 4 + q;
                    uint4 w0, w1;
                    if (p < 4) {
                        w0 = Wl4[((s6 * 4 + p) * 2 + 0) * 128 + c];
                        w1 = Wl4[((s6 * 4 + p) * 2 + 1) * 128 + c];
                    } else {
                        w0 = WGV[((prb + p) * 2 + 0) * 128 + c];
                        w1 = WGV[((prb + p) * 2 + 1) * 128 + c];
                    }
                    D8(w0, w1, aa[q])
                }
            }
            *reinterpret_cast<float4*>(&zpart[s6][8 * c])     = make_float4(a0, a1, a2, a3);
            *reinterpret_cast<float4*>(&zpart[s6][8 * c + 4]) = make_float4(a4, a5, a6, a7);
        } else {
            const int pt = t - 768;
            if (i > 0) doP3(pt);
            if (pt >= 192 && pt < 208 && i < 255) {
                int j = pt - 192;
                const float* xp = seq + (size_t)bb * 8192 + (size_t)(i + 1) * 32 + 2 * j;
                __half2 hh2 = __floats2half2_rn(xp[0], xp[1]);
                xbuf[j] = *reinterpret_cast<uint32_t*>(&hh2);
            }
            if (i > 0) {
                subsync();
                doP4(pt);
                subsync();
                doP5(pt);
            }
        }
        __syncthreads();   // B1

        // ========= LSTM i (+ xbuf -> aci copy) =========
        if (t < 256) {
            uint32_t rp0 = rp[0], rp1 = rp[1], rp2 = rp[2], rp3 = rp[3];
            uint32_t rp4 = rp[4], rp5 = rp[5], rp6 = rp[6], rp7 = rp[7];
            uint32_t rp8 = rp[8], rp9 = rp[9];
            const uint4* wrt4 = (const uint4*)WrT;   // [3][1024] uint4
            float zg4[4];
            #pragma unroll
            for (int g4 = 0; g4 < 4; ++g4) {
                const int colu = (g4 << 8) + t;
                uint4 A = wrt4[colu];
                uint4 B = wrt4[1024 + colu];
                uint4 C = wrt4[2048 + colu];
                float s = 0.0f;
                s = dot2f(A.x, rp0, s); s = dot2f(A.y, rp1, s);
                s = dot2f(A.z, rp2, s); s = dot2f(A.w, rp3, s);
                s = dot2f(B.x, rp4, s); s = dot2f(B.y, rp5, s);
                s = dot2f(B.z, rp6, s); s = dot2f(B.w, rp7, s);
                s = dot2f(C.x, rp8, s); s = dot2f(C.y, rp9, s);
                zg4[g4] = s;
            }
            float zi = lb[t]       + zg4[0];
            float zf = lb[256 + t] + zg4[1];
            float zg = lb[512 + t] + zg4[2];
            float zo = lb[768 + t] + zg4[3];
            #pragma unroll
            for (int q = 0; q < 6; ++q) {
                zi += zpart[q][t];       zf += zpart[q][256 + t];
                zg += zpart[q][512 + t]; zo += zpart[q][768 + t];
            }
            float cg = sigmoidf_(zf) * c_reg + sigmoidf_(zi) * tanhf(zg);
            c_reg = cg;
            reinterpret_cast<_Float16*>(aci)[32 + t] = (_Float16)(sigmoidf_(zo) * tanhf(cg));
        } else if (t >= 256 && t < 272 && i < 255) {
            aci[t - 256] = xbuf[t - 256];
        }
        __syncthreads();   // B2
    }

    // ---- epilogue: chain for step 255 ----
    if (t >= 768) {
        const int pt = t - 768;
        doP3(pt);
        subsync();
        doP4(pt);
        subsync();
        doP5(pt);
    }
    __syncthreads();

    // ---- final NTM output head + dense + softmax ----
    if (t < 8) {
        float s = ob[t];
        const _Float16* hrow = reinterpret_cast<const _Float16*>(aci);
        for (int u = 0; u < 256; ++u) s = fmaf((float)hrow[32 + u], ow[u * 8 + t], s);
        #pragma unroll
        for (int wi = 0; wi < 20; ++wi) s = fmaf(rds[wi], ow[(256 + wi) * 8 + t], s);
        o8[t] = fminf(fmaxf(s, -CLIPV), CLIPV);
    }
    __syncthreads();
    if (t == 0) {
        float l0 = db[0], l1 = db[1];
        #pragma unroll
        for (int k = 0; k < 8; ++k) {
            float v = o8[k];
            l0 = fmaf(v, dw[k * 2 + 0], l0);
            l1 = fmaf(v, dw[k * 2 + 1], l1);
        }
        float m = fmaxf(l0, l1);
        float q0 = expf(l0 - m), q1 = expf(l1 - m);
        float inv = 1.0f / (q0 + q1);
        out[bb * 2 + 0] = q0 * inv;
        out[bb * 2 + 1] = q1 * inv;
    }
}

extern "C" void kernel_launch(void* const* d_in, const int* in_sizes, int n_in,
                              void* d_out, int out_size, void* d_ws, size_t ws_size,
                              hipStream_t stream) {
    const float* inputs = (const float*)d_in[0];
    const float* c1w = (const float*)d_in[1];
    const float* c1b = (const float*)d_in[2];
    const float* c2w = (const float*)d_in[3];
    const float* c2b = (const float*)d_in[4];
    const float* lwx = (const float*)d_in[5];
    const float* lwh = (const float*)d_in[6];
    const float* lb  = (const float*)d_in[7];
    const float* hw  = (const float*)d_in[8];
    const float* hb  = (const float*)d_in[9];
    const float* ow  = (const float*)d_in[10];
    const float* ob  = (const float*)d_in[11];
    const float* dw  = (const float*)d_in[12];
    const float* db  = (const float*)d_in[13];
    float* out = (float*)d_out;

    float* ws  = (float*)d_ws;
    float* p1  = ws;                             // 4,194,304 f
    float* seq = ws + 4194304;                   // 2,097,152 f
    uint32_t* WG8  = (uint32_t*)(ws + 6291456);  // 147,456 u32
    uint32_t* WrT  = WG8 + 147456;               //  12,288 u32
    uint32_t* hw2G = WrT + 12288;                //  11,776 u32

    hipLaunchKernelGGL(prep_pack,   dim3(670),   dim3(256),  0, stream, lwx, lwh, hw, WG8, WrT, hw2G);
    hipLaunchKernelGGL(conv1_pool,  dim3(16384), dim3(256),  0, stream, inputs, c1w, c1b, p1);
    hipLaunchKernelGGL(conv2_pool,  dim3(8192),  dim3(256),  0, stream, p1, c2w, c2b, seq);
    hipLaunchKernelGGL(ntm_scan15,  dim3(256),   dim3(1024), 0, stream,
                       seq, WG8, WrT, hw2G, lb, hb, ow, ob, dw, db, out);
}

// Round 16
// 2661.855 us; speedup vs baseline: 2.1980x; 1.3905x over previous
//
#include <hip/hip_runtime.h>
#include <hip/hip_fp16.h>
#include <cstdint>
#include <cstddef>

// ---------------------------------------------------------------------------
// CNN (conv1+pool, conv2+pool) -> seq [256][256][32]
// NTM scan: 256 blocks x 1024 threads, 1 batch/block, 1 block/CU.
// R13 structure exactly (best: 1932us): 2 __syncthreads + 2 LDS sub-barriers,
// waves 0..7 z-GEMM | waves 8..13 chain (P3 368t / P4 128t / P5 320t) |
// wave 14 x-prefetch; then LSTM.
// R16 deltas (low-risk):
//  - __attribute__((amdgpu_waves_per_eu(4,4))): LDS already caps us at 4
//    waves/SIMD; telling the allocator lets it use up to 128 VGPRs and hoist
//    ~2x more weight loads per GEMM wave (R14's manual pipeline spilled at
//    the default 64-VGPR target).
//  - WrT coalesced [3][1024] uint4 (R14-proven) for the LSTM reads-term.
//  - subsync polls with s_sleep(2).
// ---------------------------------------------------------------------------

#define MW    20
#define NLOC  128
#define ZC    1024
#define PC    92
#define CLIPV 20.0f

__device__ __forceinline__ float sigmoidf_(float x) { return 1.0f / (1.0f + expf(-x)); }
__device__ __forceinline__ float softplusf_(float x) { return log1pf(expf(x)); }

__device__ __forceinline__ float dot2f(uint32_t w, uint32_t a, float c) {
    asm("v_dot2_f32_f16 %0, %1, %2, %0" : "+v"(c) : "v"(w), "v"(a));
    return c;
}

// pair row map (144 pairs): k<32 -> wx row k (x); k in [32,288) -> wh row k-32
__device__ __forceinline__ float wvalA(const float* wx, const float* wh, int k, int col) {
    return (k < 32) ? wx[k * ZC + col] : wh[(k - 32) * ZC + col];
}
__device__ __forceinline__ uint32_t packA(const float* wx, const float* wh, int pr, int col) {
    __half2 h = __floats2half2_rn(wvalA(wx, wh, 2 * pr, col), wvalA(wx, wh, 2 * pr + 1, col));
    return *reinterpret_cast<uint32_t*>(&h);
}

// WG8: u32 idx = ((pr*2 + j)*128 + c)*4 + m -> col = 8c + 4j + m, pr 0..143.
// WrT: u32 idx = ((j*1024)+col)*4 + qq, pair q=j*4+qq (q<10: wx rows 32..51).
// hw2: [128 up][92 col] u32.
__global__ __launch_bounds__(256) void prep_pack(const float* __restrict__ wx,
                                                 const float* __restrict__ wh,
                                                 const float* __restrict__ hw,
                                                 uint32_t* __restrict__ WG8,
                                                 uint32_t* __restrict__ WrT,
                                                 uint32_t* __restrict__ hw2) {
    int idx = blockIdx.x * 256 + threadIdx.x;
    if (idx < 147456) {
        int m = idx & 3, c = (idx >> 2) & 127, j = (idx >> 9) & 1, pr = idx >> 10;
        WG8[idx] = packA(wx, wh, pr, 8 * c + 4 * j + m);
    } else if (idx < 159744) {
        int q2 = idx - 147456;
        int qq = q2 & 3, col = (q2 >> 2) & 1023, j = q2 >> 12;
        int q = j * 4 + qq;
        if (q < 10) {
            __half2 h = __floats2half2_rn(wx[(32 + 2 * q) * ZC + col], wx[(33 + 2 * q) * ZC + col]);
            WrT[q2] = *reinterpret_cast<uint32_t*>(&h);
        } else WrT[q2] = 0u;
    } else if (idx < 171520) {
        int q3 = idx - 159744;
        int up = q3 / 92, col = q3 - up * 92;
        __half2 h = __floats2half2_rn(hw[(2 * up) * PC + col], hw[(2 * up + 1) * PC + col]);
        hw2[q3] = *reinterpret_cast<uint32_t*>(&h);
    }
}

// conv1 3x3 (1->16) SAME + relu + maxpool2
__global__ __launch_bounds__(256) void conv1_pool(const float* __restrict__ in,
                                                  const float* __restrict__ w,
                                                  const float* __restrict__ bias,
                                                  float* __restrict__ out) {
    int idx = blockIdx.x * 256 + threadIdx.x;
    if (idx >= 256 * 32 * 32 * 16) return;
    int c = idx & 15, x = (idx >> 4) & 31, y = (idx >> 9) & 31, b = idx >> 14;
    const float* inb = in + (size_t)b * 4096;
    float bv = bias[c];
    float mx = 0.0f;
    #pragma unroll
    for (int dy = 0; dy < 2; ++dy)
    #pragma unroll
    for (int dx = 0; dx < 2; ++dx) {
        int oy = 2 * y + dy, ox = 2 * x + dx;
        float s = bv;
        #pragma unroll
        for (int ky = 0; ky < 3; ++ky) {
            int iy = oy + ky - 1;
            if (iy < 0 || iy > 63) continue;
            #pragma unroll
            for (int kx = 0; kx < 3; ++kx) {
                int ix = ox + kx - 1;
                if (ix < 0 || ix > 63) continue;
                s = fmaf(inb[iy * 64 + ix], w[(ky * 3 + kx) * 16 + c], s);
            }
        }
        mx = fmaxf(mx, fmaxf(s, 0.0f));
    }
    out[idx] = mx;
}

// conv2 3x3 (16->32) SAME + relu + maxpool2
__global__ __launch_bounds__(256) void conv2_pool(const float* __restrict__ p1,
                                                  const float* __restrict__ w,
                                                  const float* __restrict__ bias,
                                                  float* __restrict__ seq) {
    int idx = blockIdx.x * 256 + threadIdx.x;
    if (idx >= 256 * 16 * 16 * 32) return;
    int c = idx & 31, x = (idx >> 5) & 15, y = (idx >> 9) & 15, b = idx >> 13;
    const float* pb = p1 + (size_t)b * (32 * 32 * 16);
    float bv = bias[c];
    float acc[4] = {bv, bv, bv, bv};
    #pragma unroll
    for (int ky = 0; ky < 3; ++ky)
    #pragma unroll
    for (int kx = 0; kx < 3; ++kx) {
        float w16[16];
        #pragma unroll
        for (int i = 0; i < 16; ++i) w16[i] = w[((ky * 3 + kx) * 16 + i) * 32 + c];
        #pragma unroll
        for (int dy = 0; dy < 2; ++dy)
        #pragma unroll
        for (int dx = 0; dx < 2; ++dx) {
            int iy = 2 * y + dy + ky - 1, ix = 2 * x + dx + kx - 1;
            if (iy < 0 || iy > 31 || ix < 0 || ix > 31) continue;
            const float4* pin4 = (const float4*)(pb + (iy * 32 + ix) * 16);
            float4 v0 = pin4[0], v1 = pin4[1], v2 = pin4[2], v3 = pin4[3];
            int a = dy * 2 + dx;
            acc[a] = fmaf(v0.x, w16[0], acc[a]);  acc[a] = fmaf(v0.y, w16[1], acc[a]);
            acc[a] = fmaf(v0.z, w16[2], acc[a]);  acc[a] = fmaf(v0.w, w16[3], acc[a]);
            acc[a] = fmaf(v1.x, w16[4], acc[a]);  acc[a] = fmaf(v1.y, w16[5], acc[a]);
            acc[a] = fmaf(v1.z, w16[6], acc[a]);  acc[a] = fmaf(v1.w, w16[7], acc[a]);
            acc[a] = fmaf(v2.x, w16[8], acc[a]);  acc[a] = fmaf(v2.y, w16[9], acc[a]);
            acc[a] = fmaf(v2.z, w16[10], acc[a]); acc[a] = fmaf(v2.w, w16[11], acc[a]);
            acc[a] = fmaf(v3.x, w16[12], acc[a]); acc[a] = fmaf(v3.y, w16[13], acc[a]);
            acc[a] = fmaf(v3.z, w16[14], acc[a]); acc[a] = fmaf(v3.w, w16[15], acc[a]);
        }
    }
    float mx = 0.0f;
    #pragma unroll
    for (int a = 0; a < 4; ++a) mx = fmaxf(mx, acc[a]);
    seq[idx] = mx;
}

// ---------------------------------------------------------------------------
// Persistent NTM scan, wave-specialized with LDS sub-barriers (R13 + tweaks).
// ---------------------------------------------------------------------------
#define PSCLIP1(col_) fminf(fmaxf(pp[0][col_] + pp[1][col_] + pp[2][col_] + pp[3][col_] + hb[col_], -CLIPV), CLIPV)

__global__ __launch_bounds__(1024)
__attribute__((amdgpu_waves_per_eu(4, 4)))
void ntm_scan16(
    const float* __restrict__ seq,
    const uint32_t* __restrict__ WG8,
    const uint32_t* __restrict__ WrT,
    const uint32_t* __restrict__ hw2G,
    const float* __restrict__ lb,
    const float* __restrict__ hb,
    const float* __restrict__ ow,
    const float* __restrict__ ob,
    const float* __restrict__ dw,
    const float* __restrict__ db,
    float* __restrict__ out)          // [256][2]
{
    __shared__ uint4 Wl4[32 * 2 * 128];               // 131072 B (8 pairs per K-quarter)
    __shared__ float zpart[4][ZC];                    // 16384 B
    __shared__ __align__(16) uint32_t aci[160];       // 640 B (x 0..15, h 16..143)
    __shared__ uint32_t xbuf[16];                     // 64 B
    __shared__ float Msh[MW][132];                    // 10560 B
    __shared__ float wprev[2][NLOC];                  // 1024 B
    __shared__ float pp[4][PC];                       // 1472 B
    __shared__ float evs[MW], avs[MW], rds[MW];       // 240 B
    __shared__ uint32_t rp[10];                       // 40 B
    __shared__ float o8[8];                           // 32 B
    __shared__ int sflag;                             // 4 B
    // total ~161.5 KB -> 1 block/CU

    const int t = threadIdx.x;
    const int bb = blockIdx.x;
    const uint4* WGV = (const uint4*)WG8;

    // ---- stage resident pairs: per K-quarter kq (36 pairs), pairs 0..7 ----
    for (int i = t; i < 8192; i += 1024) {
        int lp = i >> 8, j = (i >> 7) & 1, c = i & 127;
        int gp = (lp >> 3) * 36 + (lp & 7);
        Wl4[i] = WGV[(gp * 2 + j) * 128 + c];
    }

    // ---- init state ----
    if (t < 160) {
        uint32_t v = 0u;
        if (t < 16) {
            __half2 hh2 = __floats2half2_rn(seq[(size_t)bb * 8192 + 2 * t],
                                            seq[(size_t)bb * 8192 + 2 * t + 1]);
            v = *reinterpret_cast<uint32_t*>(&hh2);
        }
        aci[t] = v;
    }
    for (int i = t; i < MW * 132; i += 1024)
        Msh[i / 132][i - (i / 132) * 132] = 1e-6f;
    if (t < 256) wprev[t >> 7][t & 127] = 1.0f / 128.0f;
    if (t < 10) {
        __half2 hh2 = __floats2half2_rn(1e-6f, 1e-6f);
        rp[t] = *reinterpret_cast<uint32_t*>(&hh2);
    }
    if (t == 0) sflag = 0;
    float c_reg = 0.0f;   // LSTM cell: thread t<256 owns u=t
    __syncthreads();

    int svc = 0;
    auto subsync = [&]() {
        svc += 6;
        __threadfence_block();
        if ((t & 63) == 0)
            __hip_atomic_fetch_add(&sflag, 1, __ATOMIC_RELAXED, __HIP_MEMORY_SCOPE_WORKGROUP);
        while (__hip_atomic_load(&sflag, __ATOMIC_RELAXED, __HIP_MEMORY_SCOPE_WORKGROUP) < svc)
            __builtin_amdgcn_s_sleep(2);
        __threadfence_block();
    };

    // ---- chain phase bodies (waves 8..13, pt = t-512) ----
    auto doP3 = [&](int pt) {
        if (pt < 368) {
            int kq2 = pt / 92, col = pt - kq2 * 92;
            const uint32_t* hwp = hw2G + kq2 * 32 * 92 + col;
            const uint32_t* hbp = aci + 16 + kq2 * 32;
            float s = 0.0f;
            #pragma unroll 8
            for (int uu = 0; uu < 32; ++uu)
                s = dot2f(hwp[uu * 92], hbp[uu], s);
            pp[kq2][col] = s;
        }
    };
    auto doP4 = [&](int pt) {
        if (pt < 128) {
            const int l = pt & 63, hh = pt >> 6;
            const int hc = hh * 26;
            float beta  = softplusf_(PSCLIP1(hc + 20));
            float gte   = sigmoidf_(PSCLIP1(hc + 21));
            float s0r = PSCLIP1(hc + 22), s1r = PSCLIP1(hc + 23), s2r = PSCLIP1(hc + 24);
            float mS = fmaxf(s0r, fmaxf(s1r, s2r));
            float q0 = expf(s0r - mS), q1 = expf(s1r - mS), q2 = expf(s2r - mS);
            float qin = 1.0f / (q0 + q1 + q2);
            float sh0 = q0 * qin, sh1 = q1 * qin, sh2 = q2 * qin;
            float gamma = softplusf_(PSCLIP1(hc + 25)) + 1.0f;

            float kvv = (l < 20) ? tanhf(PSCLIP1(hc + l)) : 0.0f;
            float kn2 = kvv * kvv;
            #pragma unroll
            for (int o = 1; o < 64; o <<= 1) kn2 += __shfl_xor(kn2, o, 64);
            float kden = sqrtf(kn2) + 1e-8f;

            float d0 = 0, d1 = 0, m20 = 0, m21 = 0;
            #pragma unroll
            for (int wi = 0; wi < 20; ++wi) {
                float kk = __shfl(kvv, wi, 64);
                float2 mv = *reinterpret_cast<const float2*>(&Msh[wi][2 * l]);
                d0  = fmaf(kk, mv.x, d0);      d1  = fmaf(kk, mv.y, d1);
                m20 = fmaf(mv.x, mv.x, m20);   m21 = fmaf(mv.y, mv.y, m21);
            }
            float x0 = beta * (d0 / ((sqrtf(m20) + 1e-8f) * kden));
            float x1 = beta * (d1 / ((sqrtf(m21) + 1e-8f) * kden));
            float mx = fmaxf(x0, x1);
            #pragma unroll
            for (int o = 1; o < 64; o <<= 1) mx = fmaxf(mx, __shfl_xor(mx, o, 64));
            float e0 = expf(x0 - mx), e1 = expf(x1 - mx);
            float se = e0 + e1;
            #pragma unroll
            for (int o = 1; o < 64; o <<= 1) se += __shfl_xor(se, o, 64);
            float inv = 1.0f / se;
            float2 wpv = *reinterpret_cast<const float2*>(&wprev[hh][2 * l]);
            float wg0 = gte * (e0 * inv) + (1.0f - gte) * wpv.x;
            float wg1 = gte * (e1 * inv) + (1.0f - gte) * wpv.y;
            float wgm = __shfl(wg1, (l + 63) & 63, 64);
            float wgp = __shfl(wg0, (l + 1) & 63, 64);
            float wt0 = sh0 * wg1 + sh1 * wg0 + sh2 * wgm;
            float wt1 = sh0 * wgp + sh1 * wg1 + sh2 * wg0;
            float wpw0 = expf(gamma * logf(wt0 + 1e-8f));
            float wpw1 = expf(gamma * logf(wt1 + 1e-8f));
            float ssum = wpw0 + wpw1;
            #pragma unroll
            for (int o = 1; o < 64; o <<= 1) ssum += __shfl_xor(ssum, o, 64);
            float rin = 1.0f / ssum;
            *reinterpret_cast<float2*>(&wprev[hh][2 * l]) = make_float2(wpw0 * rin, wpw1 * rin);
        } else if (pt < 168) {
            int r2 = pt - 128;
            if (r2 < 20) evs[r2]      = sigmoidf_(PSCLIP1(52 + r2));
            else         avs[r2 - 20] = tanhf(PSCLIP1(72 + (r2 - 20)));
        }
    };
    auto doP5 = [&](int pt) {
        if (pt < 320) {
            int wi = pt >> 4, l16 = pt & 15;
            int n0 = l16 * 8;
            float ev = evs[wi], av = avs[wi];
            float s = 0.0f;
            #pragma unroll
            for (int n = n0; n < n0 + 8; ++n) {
                float mv = Msh[wi][n];
                s = fmaf(wprev[0][n], mv, s);
                float wwn = wprev[1][n];
                Msh[wi][n] = mv * (1.0f - wwn * ev) + wwn * av;
            }
            s += __shfl_xor(s, 1, 64); s += __shfl_xor(s, 2, 64);
            s += __shfl_xor(s, 4, 64); s += __shfl_xor(s, 8, 64);
            float sodd = __shfl_xor(s, 16, 64);
            if (l16 == 0) {
                rds[wi] = s;
                if ((wi & 1) == 0) {
                    __half2 hp = __floats2half2_rn(s, sodd);
                    rp[wi >> 1] = *reinterpret_cast<uint32_t*>(&hp);
                }
            }
        }
    };

    for (int i = 0; i < 256; ++i) {
        // ========= REGION: z-GEMM(i) || chain(i-1) || x-prefetch =========
        if (t < 512) {
            const int kq = t >> 7, c = t & 127;
            const int prb = kq * 36;
            float a0 = 0, a1 = 0, a2 = 0, a3 = 0, a4 = 0, a5 = 0, a6 = 0, a7 = 0;
            const uint4* cap = (const uint4*)(aci + prb);
            #pragma unroll
            for (int g = 0; g < 9; ++g) {
                uint4 A = cap[g];
                uint32_t aa[4] = {A.x, A.y, A.z, A.w};
                #pragma unroll
                for (int q = 0; q < 4; ++q) {
                    const int p = g * 4 + q;
                    uint4 w0, w1;
                    if (p < 8) {
                        w0 = Wl4[((kq * 8 + p) * 2 + 0) * 128 + c];
                        w1 = Wl4[((kq * 8 + p) * 2 + 1) * 128 + c];
                    } else {
                        w0 = WGV[((prb + p) * 2 + 0) * 128 + c];
                        w1 = WGV[((prb + p) * 2 + 1) * 128 + c];
                    }
                    a0 = dot2f(w0.x, aa[q], a0); a1 = dot2f(w0.y, aa[q], a1);
                    a2 = dot2f(w0.z, aa[q], a2); a3 = dot2f(w0.w, aa[q], a3);
                    a4 = dot2f(w1.x, aa[q], a4); a5 = dot2f(w1.y, aa[q], a5);
                    a6 = dot2f(w1.z, aa[q], a6); a7 = dot2f(w1.w, aa[q], a7);
                }
            }
            *reinterpret_cast<float4*>(&zpart[kq][8 * c])     = make_float4(a0, a1, a2, a3);
            *reinterpret_cast<float4*>(&zpart[kq][8 * c + 4]) = make_float4(a4, a5, a6, a7);
        } else if (t < 896) {
            if (i > 0) {
                const int pt = t - 512;
                doP3(pt);
                subsync();
                doP4(pt);
                subsync();
                doP5(pt);
            }
        } else if (t < 912 && i < 255) {
            int j = t - 896;
            const float* xp = seq + (size_t)bb * 8192 + (size_t)(i + 1) * 32 + 2 * j;
            __half2 hh2 = __floats2half2_rn(xp[0], xp[1]);
            xbuf[j] = *reinterpret_cast<uint32_t*>(&hh2);
        }
        __syncthreads();   // B1

        // ========= LSTM i (+ xbuf -> aci copy) =========
        if (t < 256) {
            uint32_t rp0 = rp[0], rp1 = rp[1], rp2 = rp[2], rp3 = rp[3];
            uint32_t rp4 = rp[4], rp5 = rp[5], rp6 = rp[6], rp7 = rp[7];
            uint32_t rp8 = rp[8], rp9 = rp[9];
            const uint4* wrt4 = (const uint4*)WrT;   // [3][1024] uint4
            float zg4[4];
            #pragma unroll
            for (int g4 = 0; g4 < 4; ++g4) {
                const int colu = (g4 << 8) + t;
                uint4 A = wrt4[colu];
                uint4 B = wrt4[1024 + colu];
                uint4 C = wrt4[2048 + colu];
                float s = 0.0f;
                s = dot2f(A.x, rp0, s); s = dot2f(A.y, rp1, s);
                s = dot2f(A.z, rp2, s); s = dot2f(A.w, rp3, s);
                s = dot2f(B.x, rp4, s); s = dot2f(B.y, rp5, s);
                s = dot2f(B.z, rp6, s); s = dot2f(B.w, rp7, s);
                s = dot2f(C.x, rp8, s); s = dot2f(C.y, rp9, s);
                zg4[g4] = s;
            }
            float zi = lb[t]       + zg4[0] + zpart[0][t]       + zpart[1][t]       + zpart[2][t]       + zpart[3][t];
            float zf = lb[256 + t] + zg4[1] + zpart[0][256 + t] + zpart[1][256 + t] + zpart[2][256 + t] + zpart[3][256 + t];
            float zg = lb[512 + t] + zg4[2] + zpart[0][512 + t] + zpart[1][512 + t] + zpart[2][512 + t] + zpart[3][512 + t];
            float zo = lb[768 + t] + zg4[3] + zpart[0][768 + t] + zpart[1][768 + t] + zpart[2][768 + t] + zpart[3][768 + t];
            float cg = sigmoidf_(zf) * c_reg + sigmoidf_(zi) * tanhf(zg);
            c_reg = cg;
            reinterpret_cast<_Float16*>(aci)[32 + t] = (_Float16)(sigmoidf_(zo) * tanhf(cg));
        } else if (t >= 256 && t < 272 && i < 255) {
            aci[t - 256] = xbuf[t - 256];
        }
        __syncthreads();   // B2
    }

    // ---- epilogue: chain for step 255 ----
    if (t >= 512 && t < 896) {
        const int pt = t - 512;
        doP3(pt);
        subsync();
        doP4(pt);
        subsync();
        doP5(pt);
    }
    __syncthreads();

    // ---- final NTM output head + dense + softmax ----
    if (t < 8) {
        float s = ob[t];
        const _Float16* hrow = reinterpret_cast<const _Float16*>(aci);
        for (int u = 0; u < 256; ++u) s = fmaf((float)hrow[32 + u], ow[u * 8 + t], s);
        #pragma unroll
        for (int wi = 0; wi < 20; ++wi) s = fmaf(rds[wi], ow[(256 + wi) * 8 + t], s);
        o8[t] = fminf(fmaxf(s, -CLIPV), CLIPV);
    }
    __syncthreads();
    if (t == 0) {
        float l0 = db[0], l1 = db[1];
        #pragma unroll
        for (int k = 0; k < 8; ++k) {
            float v = o8[k];
            l0 = fmaf(v, dw[k * 2 + 0], l0);
            l1 = fmaf(v, dw[k * 2 + 1], l1);
        }
        float m = fmaxf(l0, l1);
        float q0 = expf(l0 - m), q1 = expf(l1 - m);
        float inv = 1.0f / (q0 + q1);
        out[bb * 2 + 0] = q0 * inv;
        out[bb * 2 + 1] = q1 * inv;
    }
}

extern "C" void kernel_launch(void* const* d_in, const int* in_sizes, int n_in,
                              void* d_out, int out_size, void* d_ws, size_t ws_size,
                              hipStream_t stream) {
    const float* inputs = (const float*)d_in[0];
    const float* c1w = (const float*)d_in[1];
    const float* c1b = (const float*)d_in[2];
    const float* c2w = (const float*)d_in[3];
    const float* c2b = (const float*)d_in[4];
    const float* lwx = (const float*)d_in[5];
    const float* lwh = (const float*)d_in[6];
    const float* lb  = (const float*)d_in[7];
    const float* hw  = (const float*)d_in[8];
    const float* hb  = (const float*)d_in[9];
    const float* ow  = (const float*)d_in[10];
    const float* ob  = (const float*)d_in[11];
    const float* dw  = (const float*)d_in[12];
    const float* db  = (const float*)d_in[13];
    float* out = (float*)d_out;

    float* ws  = (float*)d_ws;
    float* p1  = ws;                             // 4,194,304 f
    float* seq = ws + 4194304;                   // 2,097,152 f
    uint32_t* WG8  = (uint32_t*)(ws + 6291456);  // 147,456 u32
    uint32_t* WrT  = WG8 + 147456;               //  12,288 u32
    uint32_t* hw2G = WrT + 12288;                //  11,776 u32

    hipLaunchKernelGGL(prep_pack,   dim3(670),   dim3(256),  0, stream, lwx, lwh, hw, WG8, WrT, hw2G);
    hipLaunchKernelGGL(conv1_pool,  dim3(16384), dim3(256),  0, stream, inputs, c1w, c1b, p1);
    hipLaunchKernelGGL(conv2_pool,  dim3(8192),  dim3(256),  0, stream, p1, c2w, c2b, seq);
    hipLaunchKernelGGL(ntm_scan16,  dim3(256),   dim3(1024), 0, stream,
                       seq, WG8, WrT, hw2G, lb, hb, ow, ob, dw, db, out);
}

// Round 17
// 1939.037 us; speedup vs baseline: 3.0174x; 1.3728x over previous
//
#include <hip/hip_runtime.h>
#include <hip/hip_fp16.h>
#include <cstdint>
#include <cstddef>

// ---------------------------------------------------------------------------
// CNN (conv1+pool, conv2+pool) -> seq [256][256][32]
// NTM scan: 256 blocks x 1024 threads, 1 batch/block, 1 block/CU.
// TWO __syncthreads per step + 2 LDS sub-barriers (6 chain waves only):
//  REGION i:
//    waves 0..7  : full z-GEMM step i (144 pairs: 32 LDS-resident 128KB,
//                  112 streamed 448KB as ONE uninterrupted burst)
//    waves 8..13 : NTM chain step i-1 at full density:
//                  P3(368t) -[subsync]- P4(128t)+ea(40t) -[subsync]- P5(320t)
//    wave 14     : prefetch x_{i+1} -> xbuf
//  LSTM i: z = sum(zpart) + WrT*rp + bias -> h_i; copy xbuf -> aci.
// Reads enter z ONLY via rp (10 fp16 pairs) x WrT (R8-R10 trick).
// ci slots (u32 pairs): x 0..15, h 16..143. Chain state (M, wprev, rp) in LDS.
// This is the R13 configuration (best measured: 1932 us) reinstated after
// R14/R15/R16 falsified manual pipelining, wave rebalance, and allocator
// hints respectively.
// ---------------------------------------------------------------------------

#define MW    20
#define NLOC  128
#define ZC    1024
#define PC    92
#define CLIPV 20.0f

__device__ __forceinline__ float sigmoidf_(float x) { return 1.0f / (1.0f + expf(-x)); }
__device__ __forceinline__ float softplusf_(float x) { return log1pf(expf(x)); }

__device__ __forceinline__ float dot2f(uint32_t w, uint32_t a, float c) {
    asm("v_dot2_f32_f16 %0, %1, %2, %0" : "+v"(c) : "v"(w), "v"(a));
    return c;
}

// pair row map (144 pairs): k<32 -> wx row k (x); k in [32,288) -> wh row k-32
__device__ __forceinline__ float wvalA(const float* wx, const float* wh, int k, int col) {
    return (k < 32) ? wx[k * ZC + col] : wh[(k - 32) * ZC + col];
}
__device__ __forceinline__ uint32_t packA(const float* wx, const float* wh, int pr, int col) {
    __half2 h = __floats2half2_rn(wvalA(wx, wh, 2 * pr, col), wvalA(wx, wh, 2 * pr + 1, col));
    return *reinterpret_cast<uint32_t*>(&h);
}

// WG8: u32 idx = ((pr*2 + j)*128 + c)*4 + m -> col = 8c + 4j + m, pr 0..143.
// WrT: [1024 cols][12] u32 (reads pairs q<10: wx rows 32..51), else 0.
// hw2: [128 up][92 col] u32.
__global__ __launch_bounds__(256) void prep_pack(const float* __restrict__ wx,
                                                 const float* __restrict__ wh,
                                                 const float* __restrict__ hw,
                                                 uint32_t* __restrict__ WG8,
                                                 uint32_t* __restrict__ WrT,
                                                 uint32_t* __restrict__ hw2) {
    int idx = blockIdx.x * 256 + threadIdx.x;
    if (idx < 147456) {
        int m = idx & 3, c = (idx >> 2) & 127, j = (idx >> 9) & 1, pr = idx >> 10;
        WG8[idx] = packA(wx, wh, pr, 8 * c + 4 * j + m);
    } else if (idx < 159744) {
        int q2 = idx - 147456;
        int col = q2 / 12, q = q2 - col * 12;
        if (q < 10) {
            __half2 h = __floats2half2_rn(wx[(32 + 2 * q) * ZC + col], wx[(33 + 2 * q) * ZC + col]);
            WrT[q2] = *reinterpret_cast<uint32_t*>(&h);
        } else WrT[q2] = 0u;
    } else if (idx < 171520) {
        int q3 = idx - 159744;
        int up = q3 / 92, col = q3 - up * 92;
        __half2 h = __floats2half2_rn(hw[(2 * up) * PC + col], hw[(2 * up + 1) * PC + col]);
        hw2[q3] = *reinterpret_cast<uint32_t*>(&h);
    }
}

// conv1 3x3 (1->16) SAME + relu + maxpool2
__global__ __launch_bounds__(256) void conv1_pool(const float* __restrict__ in,
                                                  const float* __restrict__ w,
                                                  const float* __restrict__ bias,
                                                  float* __restrict__ out) {
    int idx = blockIdx.x * 256 + threadIdx.x;
    if (idx >= 256 * 32 * 32 * 16) return;
    int c = idx & 15, x = (idx >> 4) & 31, y = (idx >> 9) & 31, b = idx >> 14;
    const float* inb = in + (size_t)b * 4096;
    float bv = bias[c];
    float mx = 0.0f;
    #pragma unroll
    for (int dy = 0; dy < 2; ++dy)
    #pragma unroll
    for (int dx = 0; dx < 2; ++dx) {
        int oy = 2 * y + dy, ox = 2 * x + dx;
        float s = bv;
        #pragma unroll
        for (int ky = 0; ky < 3; ++ky) {
            int iy = oy + ky - 1;
            if (iy < 0 || iy > 63) continue;
            #pragma unroll
            for (int kx = 0; kx < 3; ++kx) {
                int ix = ox + kx - 1;
                if (ix < 0 || ix > 63) continue;
                s = fmaf(inb[iy * 64 + ix], w[(ky * 3 + kx) * 16 + c], s);
            }
        }
        mx = fmaxf(mx, fmaxf(s, 0.0f));
    }
    out[idx] = mx;
}

// conv2 3x3 (16->32) SAME + relu + maxpool2
__global__ __launch_bounds__(256) void conv2_pool(const float* __restrict__ p1,
                                                  const float* __restrict__ w,
                                                  const float* __restrict__ bias,
                                                  float* __restrict__ seq) {
    int idx = blockIdx.x * 256 + threadIdx.x;
    if (idx >= 256 * 16 * 16 * 32) return;
    int c = idx & 31, x = (idx >> 5) & 15, y = (idx >> 9) & 15, b = idx >> 13;
    const float* pb = p1 + (size_t)b * (32 * 32 * 16);
    float bv = bias[c];
    float acc[4] = {bv, bv, bv, bv};
    #pragma unroll
    for (int ky = 0; ky < 3; ++ky)
    #pragma unroll
    for (int kx = 0; kx < 3; ++kx) {
        float w16[16];
        #pragma unroll
        for (int i = 0; i < 16; ++i) w16[i] = w[((ky * 3 + kx) * 16 + i) * 32 + c];
        #pragma unroll
        for (int dy = 0; dy < 2; ++dy)
        #pragma unroll
        for (int dx = 0; dx < 2; ++dx) {
            int iy = 2 * y + dy + ky - 1, ix = 2 * x + dx + kx - 1;
            if (iy < 0 || iy > 31 || ix < 0 || ix > 31) continue;
            const float4* pin4 = (const float4*)(pb + (iy * 32 + ix) * 16);
            float4 v0 = pin4[0], v1 = pin4[1], v2 = pin4[2], v3 = pin4[3];
            int a = dy * 2 + dx;
            acc[a] = fmaf(v0.x, w16[0], acc[a]);  acc[a] = fmaf(v0.y, w16[1], acc[a]);
            acc[a] = fmaf(v0.z, w16[2], acc[a]);  acc[a] = fmaf(v0.w, w16[3], acc[a]);
            acc[a] = fmaf(v1.x, w16[4], acc[a]);  acc[a] = fmaf(v1.y, w16[5], acc[a]);
            acc[a] = fmaf(v1.z, w16[6], acc[a]);  acc[a] = fmaf(v1.w, w16[7], acc[a]);
            acc[a] = fmaf(v2.x, w16[8], acc[a]);  acc[a] = fmaf(v2.y, w16[9], acc[a]);
            acc[a] = fmaf(v2.z, w16[10], acc[a]); acc[a] = fmaf(v2.w, w16[11], acc[a]);
            acc[a] = fmaf(v3.x, w16[12], acc[a]); acc[a] = fmaf(v3.y, w16[13], acc[a]);
            acc[a] = fmaf(v3.z, w16[14], acc[a]); acc[a] = fmaf(v3.w, w16[15], acc[a]);
        }
    }
    float mx = 0.0f;
    #pragma unroll
    for (int a = 0; a < 4; ++a) mx = fmaxf(mx, acc[a]);
    seq[idx] = mx;
}

// ---------------------------------------------------------------------------
// Persistent NTM scan, wave-specialized with LDS sub-barriers.
// ---------------------------------------------------------------------------
#define PSCLIP1(col_) fminf(fmaxf(pp[0][col_] + pp[1][col_] + pp[2][col_] + pp[3][col_] + hb[col_], -CLIPV), CLIPV)

__global__ __launch_bounds__(1024, 4) void ntm_scan13(
    const float* __restrict__ seq,
    const uint32_t* __restrict__ WG8,
    const uint32_t* __restrict__ WrT,
    const uint32_t* __restrict__ hw2G,
    const float* __restrict__ lb,
    const float* __restrict__ hb,
    const float* __restrict__ ow,
    const float* __restrict__ ob,
    const float* __restrict__ dw,
    const float* __restrict__ db,
    float* __restrict__ out)          // [256][2]
{
    __shared__ uint4 Wl4[32 * 2 * 128];               // 131072 B (8 pairs per K-quarter)
    __shared__ float zpart[4][ZC];                    // 16384 B
    __shared__ __align__(16) uint32_t aci[160];       // 640 B (x 0..15, h 16..143)
    __shared__ uint32_t xbuf[16];                     // 64 B
    __shared__ float Msh[MW][132];                    // 10560 B
    __shared__ float wprev[2][NLOC];                  // 1024 B
    __shared__ float pp[4][PC];                       // 1472 B
    __shared__ float evs[MW], avs[MW], rds[MW];       // 240 B
    __shared__ uint32_t rp[10];                       // 40 B
    __shared__ float o8[8];                           // 32 B
    __shared__ int sflag;                             // 4 B
    // total ~161.5 KB -> 1 block/CU

    const int t = threadIdx.x;
    const int bb = blockIdx.x;
    const uint4* WGV = (const uint4*)WG8;

    // ---- stage resident pairs: per K-quarter kq (36 pairs), pairs 0..7 ----
    for (int i = t; i < 8192; i += 1024) {
        int lp = i >> 8, j = (i >> 7) & 1, c = i & 127;
        int gp = (lp >> 3) * 36 + (lp & 7);
        Wl4[i] = WGV[(gp * 2 + j) * 128 + c];
    }

    // ---- init state ----
    if (t < 160) {
        uint32_t v = 0u;
        if (t < 16) {
            __half2 hh2 = __floats2half2_rn(seq[(size_t)bb * 8192 + 2 * t],
                                            seq[(size_t)bb * 8192 + 2 * t + 1]);
            v = *reinterpret_cast<uint32_t*>(&hh2);
        }
        aci[t] = v;
    }
    for (int i = t; i < MW * 132; i += 1024)
        Msh[i / 132][i - (i / 132) * 132] = 1e-6f;
    if (t < 256) wprev[t >> 7][t & 127] = 1.0f / 128.0f;
    if (t < 10) {
        __half2 hh2 = __floats2half2_rn(1e-6f, 1e-6f);
        rp[t] = *reinterpret_cast<uint32_t*>(&hh2);
    }
    if (t == 0) sflag = 0;
    float c_reg = 0.0f;   // LSTM cell: thread t<256 owns u=t
    __syncthreads();

    int svc = 0;
    auto subsync = [&]() {
        svc += 6;
        __threadfence_block();
        if ((t & 63) == 0)
            __hip_atomic_fetch_add(&sflag, 1, __ATOMIC_RELAXED, __HIP_MEMORY_SCOPE_WORKGROUP);
        while (__hip_atomic_load(&sflag, __ATOMIC_RELAXED, __HIP_MEMORY_SCOPE_WORKGROUP) < svc)
            __builtin_amdgcn_s_sleep(1);
        __threadfence_block();
    };

    // ---- chain phase bodies (waves 8..13, pt = t-512) ----
    auto doP3 = [&](int pt) {
        if (pt < 368) {
            int kq2 = pt / 92, col = pt - kq2 * 92;
            const uint32_t* hwp = hw2G + kq2 * 32 * 92 + col;
            const uint32_t* hbp = aci + 16 + kq2 * 32;
            float s = 0.0f;
            #pragma unroll 8
            for (int uu = 0; uu < 32; ++uu)
                s = dot2f(hwp[uu * 92], hbp[uu], s);
            pp[kq2][col] = s;
        }
    };
    auto doP4 = [&](int pt) {
        if (pt < 128) {
            const int l = pt & 63, hh = pt >> 6;
            const int hc = hh * 26;
            float beta  = softplusf_(PSCLIP1(hc + 20));
            float gte   = sigmoidf_(PSCLIP1(hc + 21));
            float s0r = PSCLIP1(hc + 22), s1r = PSCLIP1(hc + 23), s2r = PSCLIP1(hc + 24);
            float mS = fmaxf(s0r, fmaxf(s1r, s2r));
            float q0 = expf(s0r - mS), q1 = expf(s1r - mS), q2 = expf(s2r - mS);
            float qin = 1.0f / (q0 + q1 + q2);
            float sh0 = q0 * qin, sh1 = q1 * qin, sh2 = q2 * qin;
            float gamma = softplusf_(PSCLIP1(hc + 25)) + 1.0f;

            float kvv = (l < 20) ? tanhf(PSCLIP1(hc + l)) : 0.0f;
            float kn2 = kvv * kvv;
            #pragma unroll
            for (int o = 1; o < 64; o <<= 1) kn2 += __shfl_xor(kn2, o, 64);
            float kden = sqrtf(kn2) + 1e-8f;

            float d0 = 0, d1 = 0, m20 = 0, m21 = 0;
            #pragma unroll
            for (int wi = 0; wi < 20; ++wi) {
                float kk = __shfl(kvv, wi, 64);
                float2 mv = *reinterpret_cast<const float2*>(&Msh[wi][2 * l]);
                d0  = fmaf(kk, mv.x, d0);      d1  = fmaf(kk, mv.y, d1);
                m20 = fmaf(mv.x, mv.x, m20);   m21 = fmaf(mv.y, mv.y, m21);
            }
            float x0 = beta * (d0 / ((sqrtf(m20) + 1e-8f) * kden));
            float x1 = beta * (d1 / ((sqrtf(m21) + 1e-8f) * kden));
            float mx = fmaxf(x0, x1);
            #pragma unroll
            for (int o = 1; o < 64; o <<= 1) mx = fmaxf(mx, __shfl_xor(mx, o, 64));
            float e0 = expf(x0 - mx), e1 = expf(x1 - mx);
            float se = e0 + e1;
            #pragma unroll
            for (int o = 1; o < 64; o <<= 1) se += __shfl_xor(se, o, 64);
            float inv = 1.0f / se;
            float2 wpv = *reinterpret_cast<const float2*>(&wprev[hh][2 * l]);
            float wg0 = gte * (e0 * inv) + (1.0f - gte) * wpv.x;
            float wg1 = gte * (e1 * inv) + (1.0f - gte) * wpv.y;
            float wgm = __shfl(wg1, (l + 63) & 63, 64);
            float wgp = __shfl(wg0, (l + 1) & 63, 64);
            float wt0 = sh0 * wg1 + sh1 * wg0 + sh2 * wgm;
            float wt1 = sh0 * wgp + sh1 * wg1 + sh2 * wg0;
            float wpw0 = expf(gamma * logf(wt0 + 1e-8f));
            float wpw1 = expf(gamma * logf(wt1 + 1e-8f));
            float ssum = wpw0 + wpw1;
            #pragma unroll
            for (int o = 1; o < 64; o <<= 1) ssum += __shfl_xor(ssum, o, 64);
            float rin = 1.0f / ssum;
            *reinterpret_cast<float2*>(&wprev[hh][2 * l]) = make_float2(wpw0 * rin, wpw1 * rin);
        } else if (pt < 168) {
            int r2 = pt - 128;
            if (r2 < 20) evs[r2]      = sigmoidf_(PSCLIP1(52 + r2));
            else         avs[r2 - 20] = tanhf(PSCLIP1(72 + (r2 - 20)));
        }
    };
    auto doP5 = [&](int pt) {
        if (pt < 320) {
            int wi = pt >> 4, l16 = pt & 15;
            int n0 = l16 * 8;
            float ev = evs[wi], av = avs[wi];
            float s = 0.0f;
            #pragma unroll
            for (int n = n0; n < n0 + 8; ++n) {
                float mv = Msh[wi][n];
                s = fmaf(wprev[0][n], mv, s);
                float wwn = wprev[1][n];
                Msh[wi][n] = mv * (1.0f - wwn * ev) + wwn * av;
            }
            s += __shfl_xor(s, 1, 64); s += __shfl_xor(s, 2, 64);
            s += __shfl_xor(s, 4, 64); s += __shfl_xor(s, 8, 64);
            float sodd = __shfl_xor(s, 16, 64);
            if (l16 == 0) {
                rds[wi] = s;
                if ((wi & 1) == 0) {
                    __half2 hp = __floats2half2_rn(s, sodd);
                    rp[wi >> 1] = *reinterpret_cast<uint32_t*>(&hp);
                }
            }
        }
    };

    for (int i = 0; i < 256; ++i) {
        // ========= REGION: z-GEMM(i) || chain(i-1) || x-prefetch =========
        if (t < 512) {
            const int kq = t >> 7, c = t & 127;
            const int prb = kq * 36;
            float a0 = 0, a1 = 0, a2 = 0, a3 = 0, a4 = 0, a5 = 0, a6 = 0, a7 = 0;
            const uint4* cap = (const uint4*)(aci + prb);
            #pragma unroll
            for (int g = 0; g < 9; ++g) {
                uint4 A = cap[g];
                uint32_t aa[4] = {A.x, A.y, A.z, A.w};
                #pragma unroll
                for (int q = 0; q < 4; ++q) {
                    const int p = g * 4 + q;
                    uint4 w0, w1;
                    if (p < 8) {
                        w0 = Wl4[((kq * 8 + p) * 2 + 0) * 128 + c];
                        w1 = Wl4[((kq * 8 + p) * 2 + 1) * 128 + c];
                    } else {
                        w0 = WGV[((prb + p) * 2 + 0) * 128 + c];
                        w1 = WGV[((prb + p) * 2 + 1) * 128 + c];
                    }
                    a0 = dot2f(w0.x, aa[q], a0); a1 = dot2f(w0.y, aa[q], a1);
                    a2 = dot2f(w0.z, aa[q], a2); a3 = dot2f(w0.w, aa[q], a3);
                    a4 = dot2f(w1.x, aa[q], a4); a5 = dot2f(w1.y, aa[q], a5);
                    a6 = dot2f(w1.z, aa[q], a6); a7 = dot2f(w1.w, aa[q], a7);
                }
            }
            *reinterpret_cast<float4*>(&zpart[kq][8 * c])     = make_float4(a0, a1, a2, a3);
            *reinterpret_cast<float4*>(&zpart[kq][8 * c + 4]) = make_float4(a4, a5, a6, a7);
        } else if (t < 896) {
            if (i > 0) {
                const int pt = t - 512;
                doP3(pt);
                subsync();
                doP4(pt);
                subsync();
                doP5(pt);
            }
        } else if (t < 912 && i < 255) {
            int j = t - 896;
            const float* xp = seq + (size_t)bb * 8192 + (size_t)(i + 1) * 32 + 2 * j;
            __half2 hh2 = __floats2half2_rn(xp[0], xp[1]);
            xbuf[j] = *reinterpret_cast<uint32_t*>(&hh2);
        }
        __syncthreads();   // B1

        // ========= LSTM i (+ xbuf -> aci copy) =========
        if (t < 256) {
            uint32_t rp0 = rp[0], rp1 = rp[1], rp2 = rp[2], rp3 = rp[3];
            uint32_t rp4 = rp[4], rp5 = rp[5], rp6 = rp[6], rp7 = rp[7];
            uint32_t rp8 = rp[8], rp9 = rp[9];
            float zg4[4];
            #pragma unroll
            for (int g4 = 0; g4 < 4; ++g4) {
                const uint4* wp = (const uint4*)(WrT + ((g4 << 8) + t) * 12);
                uint4 A = wp[0], B = wp[1], C = wp[2];
                float s = 0.0f;
                s = dot2f(A.x, rp0, s); s = dot2f(A.y, rp1, s);
                s = dot2f(A.z, rp2, s); s = dot2f(A.w, rp3, s);
                s = dot2f(B.x, rp4, s); s = dot2f(B.y, rp5, s);
                s = dot2f(B.z, rp6, s); s = dot2f(B.w, rp7, s);
                s = dot2f(C.x, rp8, s); s = dot2f(C.y, rp9, s);
                zg4[g4] = s;
            }
            float zi = lb[t]       + zg4[0] + zpart[0][t]       + zpart[1][t]       + zpart[2][t]       + zpart[3][t];
            float zf = lb[256 + t] + zg4[1] + zpart[0][256 + t] + zpart[1][256 + t] + zpart[2][256 + t] + zpart[3][256 + t];
            float zg = lb[512 + t] + zg4[2] + zpart[0][512 + t] + zpart[1][512 + t] + zpart[2][512 + t] + zpart[3][512 + t];
            float zo = lb[768 + t] + zg4[3] + zpart[0][768 + t] + zpart[1][768 + t] + zpart[2][768 + t] + zpart[3][768 + t];
            float cg = sigmoidf_(zf) * c_reg + sigmoidf_(zi) * tanhf(zg);
            c_reg = cg;
            reinterpret_cast<_Float16*>(aci)[32 + t] = (_Float16)(sigmoidf_(zo) * tanhf(cg));
        } else if (t >= 256 && t < 272 && i < 255) {
            aci[t - 256] = xbuf[t - 256];
        }
        __syncthreads();   // B2
    }

    // ---- epilogue: chain for step 255 ----
    if (t >= 512 && t < 896) {
        const int pt = t - 512;
        doP3(pt);
        subsync();
        doP4(pt);
        subsync();
        doP5(pt);
    }
    __syncthreads();

    // ---- final NTM output head + dense + softmax ----
    if (t < 8) {
        float s = ob[t];
        const _Float16* hrow = reinterpret_cast<const _Float16*>(aci);
        for (int u = 0; u < 256; ++u) s = fmaf((float)hrow[32 + u], ow[u * 8 + t], s);
        #pragma unroll
        for (int wi = 0; wi < 20; ++wi) s = fmaf(rds[wi], ow[(256 + wi) * 8 + t], s);
        o8[t] = fminf(fmaxf(s, -CLIPV), CLIPV);
    }
    __syncthreads();
    if (t == 0) {
        float l0 = db[0], l1 = db[1];
        #pragma unroll
        for (int k = 0; k < 8; ++k) {
            float v = o8[k];
            l0 = fmaf(v, dw[k * 2 + 0], l0);
            l1 = fmaf(v, dw[k * 2 + 1], l1);
        }
        float m = fmaxf(l0, l1);
        float q0 = expf(l0 - m), q1 = expf(l1 - m);
        float inv = 1.0f / (q0 + q1);
        out[bb * 2 + 0] = q0 * inv;
        out[bb * 2 + 1] = q1 * inv;
    }
}

extern "C" void kernel_launch(void* const* d_in, const int* in_sizes, int n_in,
                              void* d_out, int out_size, void* d_ws, size_t ws_size,
                              hipStream_t stream) {
    const float* inputs = (const float*)d_in[0];
    const float* c1w = (const float*)d_in[1];
    const float* c1b = (const float*)d_in[2];
    const float* c2w = (const float*)d_in[3];
    const float* c2b = (const float*)d_in[4];
    const float* lwx = (const float*)d_in[5];
    const float* lwh = (const float*)d_in[6];
    const float* lb  = (const float*)d_in[7];
    const float* hw  = (const float*)d_in[8];
    const float* hb  = (const float*)d_in[9];
    const float* ow  = (const float*)d_in[10];
    const float* ob  = (const float*)d_in[11];
    const float* dw  = (const float*)d_in[12];
    const float* db  = (const float*)d_in[13];
    float* out = (float*)d_out;

    float* ws  = (float*)d_ws;
    float* p1  = ws;                             // 4,194,304 f
    float* seq = ws + 4194304;                   // 2,097,152 f
    uint32_t* WG8  = (uint32_t*)(ws + 6291456);  // 147,456 u32
    uint32_t* WrT  = WG8 + 147456;               //  12,288 u32
    uint32_t* hw2G = WrT + 12288;                //  11,776 u32

    hipLaunchKernelGGL(prep_pack,   dim3(670),   dim3(256),  0, stream, lwx, lwh, hw, WG8, WrT, hw2G);
    hipLaunchKernelGGL(conv1_pool,  dim3(16384), dim3(256),  0, stream, inputs, c1w, c1b, p1);
    hipLaunchKernelGGL(conv2_pool,  dim3(8192),  dim3(256),  0, stream, p1, c2w, c2b, seq);
    hipLaunchKernelGGL(ntm_scan13,  dim3(256),   dim3(1024), 0, stream,
                       seq, WG8, WrT, hw2G, lb, hb, ow, ob, dw, db, out);
}

// Round 18
// 1933.910 us; speedup vs baseline: 3.0254x; 1.0027x over previous
//
#include <hip/hip_runtime.h>
#include <hip/hip_fp16.h>
#include <cstdint>
#include <cstddef>

// ---------------------------------------------------------------------------
// CNN (conv1+pool, conv2+pool) -> seq [256][256][32]
// NTM scan: 256 blocks x 1024 threads, 1 batch/block, 1 block/CU.
// R13 structure (2 __syncthreads + 2 LDS sub-barriers):
//  REGION i: waves 0..7 z-GEMM(i) | waves 8..13 chain(i-1) P3/P4/P5 |
//            wave 14 x-prefetch.  Then LSTM(i).
// R18 deltas (micro, mechanism-backed):
//  - thread (kq,c) now owns cols c+128m (stride 128) instead of 8c..8c+7:
//    zpart writes become 8 conflict-free scalar ds_write_b32 (was 2
//    ds_write_b128 at 16-way bank conflict). prep_pack mapping adjusted;
//    numerics identical.
//  - s_setprio(1) around the GEMM dot2 burst (T5: role-split waves exist).
// ---------------------------------------------------------------------------

#define MW    20
#define NLOC  128
#define ZC    1024
#define PC    92
#define CLIPV 20.0f

__device__ __forceinline__ float sigmoidf_(float x) { return 1.0f / (1.0f + expf(-x)); }
__device__ __forceinline__ float softplusf_(float x) { return log1pf(expf(x)); }

__device__ __forceinline__ float dot2f(uint32_t w, uint32_t a, float c) {
    asm("v_dot2_f32_f16 %0, %1, %2, %0" : "+v"(c) : "v"(w), "v"(a));
    return c;
}

// pair row map (144 pairs): k<32 -> wx row k (x); k in [32,288) -> wh row k-32
__device__ __forceinline__ float wvalA(const float* wx, const float* wh, int k, int col) {
    return (k < 32) ? wx[k * ZC + col] : wh[(k - 32) * ZC + col];
}
__device__ __forceinline__ uint32_t packA(const float* wx, const float* wh, int pr, int col) {
    __half2 h = __floats2half2_rn(wvalA(wx, wh, 2 * pr, col), wvalA(wx, wh, 2 * pr + 1, col));
    return *reinterpret_cast<uint32_t*>(&h);
}

// WG8: u32 idx = ((pr*2 + j)*128 + c)*4 + m -> col = c + 128*(4j+m), pr 0..143.
// WrT: [1024 cols][12] u32 (reads pairs q<10: wx rows 32..51), else 0.
// hw2: [128 up][92 col] u32.
__global__ __launch_bounds__(256) void prep_pack(const float* __restrict__ wx,
                                                 const float* __restrict__ wh,
                                                 const float* __restrict__ hw,
                                                 uint32_t* __restrict__ WG8,
                                                 uint32_t* __restrict__ WrT,
                                                 uint32_t* __restrict__ hw2) {
    int idx = blockIdx.x * 256 + threadIdx.x;
    if (idx < 147456) {
        int m = idx & 3, c = (idx >> 2) & 127, j = (idx >> 9) & 1, pr = idx >> 10;
        WG8[idx] = packA(wx, wh, pr, c + 128 * (4 * j + m));
    } else if (idx < 159744) {
        int q2 = idx - 147456;
        int col = q2 / 12, q = q2 - col * 12;
        if (q < 10) {
            __half2 h = __floats2half2_rn(wx[(32 + 2 * q) * ZC + col], wx[(33 + 2 * q) * ZC + col]);
            WrT[q2] = *reinterpret_cast<uint32_t*>(&h);
        } else WrT[q2] = 0u;
    } else if (idx < 171520) {
        int q3 = idx - 159744;
        int up = q3 / 92, col = q3 - up * 92;
        __half2 h = __floats2half2_rn(hw[(2 * up) * PC + col], hw[(2 * up + 1) * PC + col]);
        hw2[q3] = *reinterpret_cast<uint32_t*>(&h);
    }
}

// conv1 3x3 (1->16) SAME + relu + maxpool2
__global__ __launch_bounds__(256) void conv1_pool(const float* __restrict__ in,
                                                  const float* __restrict__ w,
                                                  const float* __restrict__ bias,
                                                  float* __restrict__ out) {
    int idx = blockIdx.x * 256 + threadIdx.x;
    if (idx >= 256 * 32 * 32 * 16) return;
    int c = idx & 15, x = (idx >> 4) & 31, y = (idx >> 9) & 31, b = idx >> 14;
    const float* inb = in + (size_t)b * 4096;
    float bv = bias[c];
    float mx = 0.0f;
    #pragma unroll
    for (int dy = 0; dy < 2; ++dy)
    #pragma unroll
    for (int dx = 0; dx < 2; ++dx) {
        int oy = 2 * y + dy, ox = 2 * x + dx;
        float s = bv;
        #pragma unroll
        for (int ky = 0; ky < 3; ++ky) {
            int iy = oy + ky - 1;
            if (iy < 0 || iy > 63) continue;
            #pragma unroll
            for (int kx = 0; kx < 3; ++kx) {
                int ix = ox + kx - 1;
                if (ix < 0 || ix > 63) continue;
                s = fmaf(inb[iy * 64 + ix], w[(ky * 3 + kx) * 16 + c], s);
            }
        }
        mx = fmaxf(mx, fmaxf(s, 0.0f));
    }
    out[idx] = mx;
}

// conv2 3x3 (16->32) SAME + relu + maxpool2
__global__ __launch_bounds__(256) void conv2_pool(const float* __restrict__ p1,
                                                  const float* __restrict__ w,
                                                  const float* __restrict__ bias,
                                                  float* __restrict__ seq) {
    int idx = blockIdx.x * 256 + threadIdx.x;
    if (idx >= 256 * 16 * 16 * 32) return;
    int c = idx & 31, x = (idx >> 5) & 15, y = (idx >> 9) & 15, b = idx >> 13;
    const float* pb = p1 + (size_t)b * (32 * 32 * 16);
    float bv = bias[c];
    float acc[4] = {bv, bv, bv, bv};
    #pragma unroll
    for (int ky = 0; ky < 3; ++ky)
    #pragma unroll
    for (int kx = 0; kx < 3; ++kx) {
        float w16[16];
        #pragma unroll
        for (int i = 0; i < 16; ++i) w16[i] = w[((ky * 3 + kx) * 16 + i) * 32 + c];
        #pragma unroll
        for (int dy = 0; dy < 2; ++dy)
        #pragma unroll
        for (int dx = 0; dx < 2; ++dx) {
            int iy = 2 * y + dy + ky - 1, ix = 2 * x + dx + kx - 1;
            if (iy < 0 || iy > 31 || ix < 0 || ix > 31) continue;
            const float4* pin4 = (const float4*)(pb + (iy * 32 + ix) * 16);
            float4 v0 = pin4[0], v1 = pin4[1], v2 = pin4[2], v3 = pin4[3];
            int a = dy * 2 + dx;
            acc[a] = fmaf(v0.x, w16[0], acc[a]);  acc[a] = fmaf(v0.y, w16[1], acc[a]);
            acc[a] = fmaf(v0.z, w16[2], acc[a]);  acc[a] = fmaf(v0.w, w16[3], acc[a]);
            acc[a] = fmaf(v1.x, w16[4], acc[a]);  acc[a] = fmaf(v1.y, w16[5], acc[a]);
            acc[a] = fmaf(v1.z, w16[6], acc[a]);  acc[a] = fmaf(v1.w, w16[7], acc[a]);
            acc[a] = fmaf(v2.x, w16[8], acc[a]);  acc[a] = fmaf(v2.y, w16[9], acc[a]);
            acc[a] = fmaf(v2.z, w16[10], acc[a]); acc[a] = fmaf(v2.w, w16[11], acc[a]);
            acc[a] = fmaf(v3.x, w16[12], acc[a]); acc[a] = fmaf(v3.y, w16[13], acc[a]);
            acc[a] = fmaf(v3.z, w16[14], acc[a]); acc[a] = fmaf(v3.w, w16[15], acc[a]);
        }
    }
    float mx = 0.0f;
    #pragma unroll
    for (int a = 0; a < 4; ++a) mx = fmaxf(mx, acc[a]);
    seq[idx] = mx;
}

// ---------------------------------------------------------------------------
// Persistent NTM scan, wave-specialized with LDS sub-barriers.
// ---------------------------------------------------------------------------
#define PSCLIP1(col_) fminf(fmaxf(pp[0][col_] + pp[1][col_] + pp[2][col_] + pp[3][col_] + hb[col_], -CLIPV), CLIPV)

__global__ __launch_bounds__(1024, 4) void ntm_scan18(
    const float* __restrict__ seq,
    const uint32_t* __restrict__ WG8,
    const uint32_t* __restrict__ WrT,
    const uint32_t* __restrict__ hw2G,
    const float* __restrict__ lb,
    const float* __restrict__ hb,
    const float* __restrict__ ow,
    const float* __restrict__ ob,
    const float* __restrict__ dw,
    const float* __restrict__ db,
    float* __restrict__ out)          // [256][2]
{
    __shared__ uint4 Wl4[32 * 2 * 128];               // 131072 B (8 pairs per K-quarter)
    __shared__ float zpart[4][ZC];                    // 16384 B
    __shared__ __align__(16) uint32_t aci[160];       // 640 B (x 0..15, h 16..143)
    __shared__ uint32_t xbuf[16];                     // 64 B
    __shared__ float Msh[MW][132];                    // 10560 B
    __shared__ float wprev[2][NLOC];                  // 1024 B
    __shared__ float pp[4][PC];                       // 1472 B
    __shared__ float evs[MW], avs[MW], rds[MW];       // 240 B
    __shared__ uint32_t rp[10];                       // 40 B
    __shared__ float o8[8];                           // 32 B
    __shared__ int sflag;                             // 4 B
    // total ~161.5 KB -> 1 block/CU

    const int t = threadIdx.x;
    const int bb = blockIdx.x;
    const uint4* WGV = (const uint4*)WG8;

    // ---- stage resident pairs: per K-quarter kq (36 pairs), pairs 0..7 ----
    for (int i = t; i < 8192; i += 1024) {
        int lp = i >> 8, j = (i >> 7) & 1, c = i & 127;
        int gp = (lp >> 3) * 36 + (lp & 7);
        Wl4[i] = WGV[(gp * 2 + j) * 128 + c];
    }

    // ---- init state ----
    if (t < 160) {
        uint32_t v = 0u;
        if (t < 16) {
            __half2 hh2 = __floats2half2_rn(seq[(size_t)bb * 8192 + 2 * t],
                                            seq[(size_t)bb * 8192 + 2 * t + 1]);
            v = *reinterpret_cast<uint32_t*>(&hh2);
        }
        aci[t] = v;
    }
    for (int i = t; i < MW * 132; i += 1024)
        Msh[i / 132][i - (i / 132) * 132] = 1e-6f;
    if (t < 256) wprev[t >> 7][t & 127] = 1.0f / 128.0f;
    if (t < 10) {
        __half2 hh2 = __floats2half2_rn(1e-6f, 1e-6f);
        rp[t] = *reinterpret_cast<uint32_t*>(&hh2);
    }
    if (t == 0) sflag = 0;
    float c_reg = 0.0f;   // LSTM cell: thread t<256 owns u=t
    __syncthreads();

    int svc = 0;
    auto subsync = [&]() {
        svc += 6;
        __threadfence_block();
        if ((t & 63) == 0)
            __hip_atomic_fetch_add(&sflag, 1, __ATOMIC_RELAXED, __HIP_MEMORY_SCOPE_WORKGROUP);
        while (__hip_atomic_load(&sflag, __ATOMIC_RELAXED, __HIP_MEMORY_SCOPE_WORKGROUP) < svc)
            __builtin_amdgcn_s_sleep(1);
        __threadfence_block();
    };

    // ---- chain phase bodies (waves 8..13, pt = t-512) ----
    auto doP3 = [&](int pt) {
        if (pt < 368) {
            int kq2 = pt / 92, col = pt - kq2 * 92;
            const uint32_t* hwp = hw2G + kq2 * 32 * 92 + col;
            const uint32_t* hbp = aci + 16 + kq2 * 32;
            float s = 0.0f;
            #pragma unroll 8
            for (int uu = 0; uu < 32; ++uu)
                s = dot2f(hwp[uu * 92], hbp[uu], s);
            pp[kq2][col] = s;
        }
    };
    auto doP4 = [&](int pt) {
        if (pt < 128) {
            const int l = pt & 63, hh = pt >> 6;
            const int hc = hh * 26;
            float beta  = softplusf_(PSCLIP1(hc + 20));
            float gte   = sigmoidf_(PSCLIP1(hc + 21));
            float s0r = PSCLIP1(hc + 22), s1r = PSCLIP1(hc + 23), s2r = PSCLIP1(hc + 24);
            float mS = fmaxf(s0r, fmaxf(s1r, s2r));
            float q0 = expf(s0r - mS), q1 = expf(s1r - mS), q2 = expf(s2r - mS);
            float qin = 1.0f / (q0 + q1 + q2);
            float sh0 = q0 * qin, sh1 = q1 * qin, sh2 = q2 * qin;
            float gamma = softplusf_(PSCLIP1(hc + 25)) + 1.0f;

            float kvv = (l < 20) ? tanhf(PSCLIP1(hc + l)) : 0.0f;
            float kn2 = kvv * kvv;
            #pragma unroll
            for (int o = 1; o < 64; o <<= 1) kn2 += __shfl_xor(kn2, o, 64);
            float kden = sqrtf(kn2) + 1e-8f;

            float d0 = 0, d1 = 0, m20 = 0, m21 = 0;
            #pragma unroll
            for (int wi = 0; wi < 20; ++wi) {
                float kk = __shfl(kvv, wi, 64);
                float2 mv = *reinterpret_cast<const float2*>(&Msh[wi][2 * l]);
                d0  = fmaf(kk, mv.x, d0);      d1  = fmaf(kk, mv.y, d1);
                m20 = fmaf(mv.x, mv.x, m20);   m21 = fmaf(mv.y, mv.y, m21);
            }
            float x0 = beta * (d0 / ((sqrtf(m20) + 1e-8f) * kden));
            float x1 = beta * (d1 / ((sqrtf(m21) + 1e-8f) * kden));
            float mx = fmaxf(x0, x1);
            #pragma unroll
            for (int o = 1; o < 64; o <<= 1) mx = fmaxf(mx, __shfl_xor(mx, o, 64));
            float e0 = expf(x0 - mx), e1 = expf(x1 - mx);
            float se = e0 + e1;
            #pragma unroll
            for (int o = 1; o < 64; o <<= 1) se += __shfl_xor(se, o, 64);
            float inv = 1.0f / se;
            float2 wpv = *reinterpret_cast<const float2*>(&wprev[hh][2 * l]);
            float wg0 = gte * (e0 * inv) + (1.0f - gte) * wpv.x;
            float wg1 = gte * (e1 * inv) + (1.0f - gte) * wpv.y;
            float wgm = __shfl(wg1, (l + 63) & 63, 64);
            float wgp = __shfl(wg0, (l + 1) & 63, 64);
            float wt0 = sh0 * wg1 + sh1 * wg0 + sh2 * wgm;
            float wt1 = sh0 * wgp + sh1 * wg1 + sh2 * wg0;
            float wpw0 = expf(gamma * logf(wt0 + 1e-8f));
            float wpw1 = expf(gamma * logf(wt1 + 1e-8f));
            float ssum = wpw0 + wpw1;
            #pragma unroll
            for (int o = 1; o < 64; o <<= 1) ssum += __shfl_xor(ssum, o, 64);
            float rin = 1.0f / ssum;
            *reinterpret_cast<float2*>(&wprev[hh][2 * l]) = make_float2(wpw0 * rin, wpw1 * rin);
        } else if (pt < 168) {
            int r2 = pt - 128;
            if (r2 < 20) evs[r2]      = sigmoidf_(PSCLIP1(52 + r2));
            else         avs[r2 - 20] = tanhf(PSCLIP1(72 + (r2 - 20)));
        }
    };
    auto doP5 = [&](int pt) {
        if (pt < 320) {
            int wi = pt >> 4, l16 = pt & 15;
            int n0 = l16 * 8;
            float ev = evs[wi], av = avs[wi];
            float s = 0.0f;
            #pragma unroll
            for (int n = n0; n < n0 + 8; ++n) {
                float mv = Msh[wi][n];
                s = fmaf(wprev[0][n], mv, s);
                float wwn = wprev[1][n];
                Msh[wi][n] = mv * (1.0f - wwn * ev) + wwn * av;
            }
            s += __shfl_xor(s, 1, 64); s += __shfl_xor(s, 2, 64);
            s += __shfl_xor(s, 4, 64); s += __shfl_xor(s, 8, 64);
            float sodd = __shfl_xor(s, 16, 64);
            if (l16 == 0) {
                rds[wi] = s;
                if ((wi & 1) == 0) {
                    __half2 hp = __floats2half2_rn(s, sodd);
                    rp[wi >> 1] = *reinterpret_cast<uint32_t*>(&hp);
                }
            }
        }
    };

    for (int i = 0; i < 256; ++i) {
        // ========= REGION: z-GEMM(i) || chain(i-1) || x-prefetch =========
        if (t < 512) {
            const int kq = t >> 7, c = t & 127;
            const int prb = kq * 36;
            float a0 = 0, a1 = 0, a2 = 0, a3 = 0, a4 = 0, a5 = 0, a6 = 0, a7 = 0;
            const uint4* cap = (const uint4*)(aci + prb);
            __builtin_amdgcn_s_setprio(1);
            #pragma unroll
            for (int g = 0; g < 9; ++g) {
                uint4 A = cap[g];
                uint32_t aa[4] = {A.x, A.y, A.z, A.w};
                #pragma unroll
                for (int q = 0; q < 4; ++q) {
                    const int p = g * 4 + q;
                    uint4 w0, w1;
                    if (p < 8) {
                        w0 = Wl4[((kq * 8 + p) * 2 + 0) * 128 + c];
                        w1 = Wl4[((kq * 8 + p) * 2 + 1) * 128 + c];
                    } else {
                        w0 = WGV[((prb + p) * 2 + 0) * 128 + c];
                        w1 = WGV[((prb + p) * 2 + 1) * 128 + c];
                    }
                    a0 = dot2f(w0.x, aa[q], a0); a1 = dot2f(w0.y, aa[q], a1);
                    a2 = dot2f(w0.z, aa[q], a2); a3 = dot2f(w0.w, aa[q], a3);
                    a4 = dot2f(w1.x, aa[q], a4); a5 = dot2f(w1.y, aa[q], a5);
                    a6 = dot2f(w1.z, aa[q], a6); a7 = dot2f(w1.w, aa[q], a7);
                }
            }
            __builtin_amdgcn_s_setprio(0);
            // cols c + 128*m: conflict-free scalar LDS writes (4B lane stride)
            zpart[kq][c]       = a0;  zpart[kq][c + 128] = a1;
            zpart[kq][c + 256] = a2;  zpart[kq][c + 384] = a3;
            zpart[kq][c + 512] = a4;  zpart[kq][c + 640] = a5;
            zpart[kq][c + 768] = a6;  zpart[kq][c + 896] = a7;
        } else if (t < 896) {
            if (i > 0) {
                const int pt = t - 512;
                doP3(pt);
                subsync();
                doP4(pt);
                subsync();
                doP5(pt);
            }
        } else if (t < 912 && i < 255) {
            int j = t - 896;
            const float* xp = seq + (size_t)bb * 8192 + (size_t)(i + 1) * 32 + 2 * j;
            __half2 hh2 = __floats2half2_rn(xp[0], xp[1]);
            xbuf[j] = *reinterpret_cast<uint32_t*>(&hh2);
        }
        __syncthreads();   // B1

        // ========= LSTM i (+ xbuf -> aci copy) =========
        if (t < 256) {
            uint32_t rp0 = rp[0], rp1 = rp[1], rp2 = rp[2], rp3 = rp[3];
            uint32_t rp4 = rp[4], rp5 = rp[5], rp6 = rp[6], rp7 = rp[7];
            uint32_t rp8 = rp[8], rp9 = rp[9];
            float zg4[4];
            #pragma unroll
            for (int g4 = 0; g4 < 4; ++g4) {
                const uint4* wp = (const uint4*)(WrT + ((g4 << 8) + t) * 12);
                uint4 A = wp[0], B = wp[1], C = wp[2];
                float s = 0.0f;
                s = dot2f(A.x, rp0, s); s = dot2f(A.y, rp1, s);
                s = dot2f(A.z, rp2, s); s = dot2f(A.w, rp3, s);
                s = dot2f(B.x, rp4, s); s = dot2f(B.y, rp5, s);
                s = dot2f(B.z, rp6, s); s = dot2f(B.w, rp7, s);
                s = dot2f(C.x, rp8, s); s = dot2f(C.y, rp9, s);
                zg4[g4] = s;
            }
            float zi = lb[t]       + zg4[0] + zpart[0][t]       + zpart[1][t]       + zpart[2][t]       + zpart[3][t];
            float zf = lb[256 + t] + zg4[1] + zpart[0][256 + t] + zpart[1][256 + t] + zpart[2][256 + t] + zpart[3][256 + t];
            float zg = lb[512 + t] + zg4[2] + zpart[0][512 + t] + zpart[1][512 + t] + zpart[2][512 + t] + zpart[3][512 + t];
            float zo = lb[768 + t] + zg4[3] + zpart[0][768 + t] + zpart[1][768 + t] + zpart[2][768 + t] + zpart[3][768 + t];
            float cg = sigmoidf_(zf) * c_reg + sigmoidf_(zi) * tanhf(zg);
            c_reg = cg;
            reinterpret_cast<_Float16*>(aci)[32 + t] = (_Float16)(sigmoidf_(zo) * tanhf(cg));
        } else if (t >= 256 && t < 272 && i < 255) {
            aci[t - 256] = xbuf[t - 256];
        }
        __syncthreads();   // B2
    }

    // ---- epilogue: chain for step 255 ----
    if (t >= 512 && t < 896) {
        const int pt = t - 512;
        doP3(pt);
        subsync();
        doP4(pt);
        subsync();
        doP5(pt);
    }
    __syncthreads();

    // ---- final NTM output head + dense + softmax ----
    if (t < 8) {
        float s = ob[t];
        const _Float16* hrow = reinterpret_cast<const _Float16*>(aci);
        for (int u = 0; u < 256; ++u) s = fmaf((float)hrow[32 + u], ow[u * 8 + t], s);
        #pragma unroll
        for (int wi = 0; wi < 20; ++wi) s = fmaf(rds[wi], ow[(256 + wi) * 8 + t], s);
        o8[t] = fminf(fmaxf(s, -CLIPV), CLIPV);
    }
    __syncthreads();
    if (t == 0) {
        float l0 = db[0], l1 = db[1];
        #pragma unroll
        for (int k = 0; k < 8; ++k) {
            float v = o8[k];
            l0 = fmaf(v, dw[k * 2 + 0], l0);
            l1 = fmaf(v, dw[k * 2 + 1], l1);
        }
        float m = fmaxf(l0, l1);
        float q0 = expf(l0 - m), q1 = expf(l1 - m);
        float inv = 1.0f / (q0 + q1);
        out[bb * 2 + 0] = q0 * inv;
        out[bb * 2 + 1] = q1 * inv;
    }
}

extern "C" void kernel_launch(void* const* d_in, const int* in_sizes, int n_in,
                              void* d_out, int out_size, void* d_ws, size_t ws_size,
                              hipStream_t stream) {
    const float* inputs = (const float*)d_in[0];
    const float* c1w = (const float*)d_in[1];
    const float* c1b = (const float*)d_in[2];
    const float* c2w = (const float*)d_in[3];
    const float* c2b = (const float*)d_in[4];
    const float* lwx = (const float*)d_in[5];
    const float* lwh = (const float*)d_in[6];
    const float* lb  = (const float*)d_in[7];
    const float* hw  = (const float*)d_in[8];
    const float* hb  = (const float*)d_in[9];
    const float* ow  = (const float*)d_in[10];
    const float* ob  = (const float*)d_in[11];
    const float* dw  = (const float*)d_in[12];
    const float* db  = (const float*)d_in[13];
    float* out = (float*)d_out;

    float* ws  = (float*)d_ws;
    float* p1  = ws;                             // 4,194,304 f
    float* seq = ws + 4194304;                   // 2,097,152 f
    uint32_t* WG8  = (uint32_t*)(ws + 6291456);  // 147,456 u32
    uint32_t* WrT  = WG8 + 147456;               //  12,288 u32
    uint32_t* hw2G = WrT + 12288;                //  11,776 u32

    hipLaunchKernelGGL(prep_pack,   dim3(670),   dim3(256),  0, stream, lwx, lwh, hw, WG8, WrT, hw2G);
    hipLaunchKernelGGL(conv1_pool,  dim3(16384), dim3(256),  0, stream, inputs, c1w, c1b, p1);
    hipLaunchKernelGGL(conv2_pool,  dim3(8192),  dim3(256),  0, stream, p1, c2w, c2b, seq);
    hipLaunchKernelGGL(ntm_scan18,  dim3(256),   dim3(1024), 0, stream,
                       seq, WG8, WrT, hw2G, lb, hb, ow, ob, dw, db, out);
}